// Round 1
// baseline (4849.695 us; speedup 1.0000x reference)
//
#include <hip/hip_runtime.h>
#include <math.h>

// Problem constants (fixed by setup_inputs)
#define NB   2
#define CIN  256
#define IMH  80
#define IMW  80
#define NPIX (IMH*IMW)   // 6400
#define CK   128
#define CVC  256
#define COUTC 256
#define BN_EPS 1e-5f

// ---------------- kq = BN(1x1 conv(x)) ; layout [B, CK, N] ----------------
__global__ void kq_kernel(const float* __restrict__ x, const float* __restrict__ wk,
                          const float* __restrict__ bk, const float* __restrict__ gamma,
                          const float* __restrict__ beta, const float* __restrict__ rmean,
                          const float* __restrict__ rvar, float* __restrict__ kq)
{
    int idx = blockIdx.x * 256 + threadIdx.x;          // b*CK*NPIX + ck*NPIX + n
    if (idx >= NB * CK * NPIX) return;
    int n  = idx % NPIX;
    int ck = (idx / NPIX) % CK;
    int b  = idx / (NPIX * CK);
    const float* xp = x + (size_t)b * CIN * NPIX + n;  // coalesced across n
    const float* wp = wk + ck * CIN;                   // broadcast within wave
    float acc = 0.f;
    #pragma unroll 8
    for (int c = 0; c < CIN; ++c)
        acc = fmaf(wp[c], xp[(size_t)c * NPIX], acc);
    acc += bk[ck];
    float inv = gamma[ck] * rsqrtf(rvar[ck] + BN_EPS);
    kq[idx] = acc * inv + (beta[ck] - rmean[ck] * inv);
}

// ---------------- value = 3x3 conv(x), pad 1 ; layout [B, CVC, N] ----------------
__global__ void conv3_kernel(const float* __restrict__ x, const float* __restrict__ wv,
                             const float* __restrict__ bv, float* __restrict__ val)
{
    int idx = blockIdx.x * 256 + threadIdx.x;          // b*CVC*NPIX + cv*NPIX + n
    if (idx >= NB * CVC * NPIX) return;
    int n  = idx % NPIX;
    int cv = (idx / NPIX) % CVC;
    int b  = idx / (NPIX * CVC);
    int h = n / IMW, w = n % IMW;
    const float* xb = x + (size_t)b * CIN * NPIX;
    const float* wp = wv + (size_t)cv * CIN * 9;
    float acc = bv[cv];
    for (int c = 0; c < CIN; ++c) {
        const float* xc = xb + (size_t)c * NPIX;
        const float* wc = wp + c * 9;
        #pragma unroll
        for (int dh = 0; dh < 3; ++dh) {
            int hh = h + dh - 1;
            if ((unsigned)hh >= IMH) continue;
            #pragma unroll
            for (int dw = 0; dw < 3; ++dw) {
                int ww2 = w + dw - 1;
                if ((unsigned)ww2 >= IMW) continue;
                acc = fmaf(wc[dh*3+dw], xc[hh*IMW + ww2], acc);
            }
        }
    }
    val[idx] = acc;
}

// ---------------- flash attention: ctx[b,cv,n] = softmax(kq^T kq) @ value^T ----------------
#define TQ 32
#define TK 32
#define QS_LD 132   // 128 + 4: rows 16B-aligned for float4 ds reads
#define VS_LD 260   // 256 + 4
#define PS_LD 33

__global__ __launch_bounds__(256) void attn_kernel(const float* __restrict__ kq,
                                                   const float* __restrict__ val,
                                                   float* __restrict__ ctx)
{
    __shared__ float Qs[TQ][QS_LD];
    __shared__ float Ks[TK][QS_LD];
    __shared__ float Vs[TK][VS_LD];
    __shared__ float Ps[TQ][PS_LD];
    __shared__ float mrow[TQ], lrow[TQ], arow[TQ];

    const int tid = threadIdx.x;
    const int b   = blockIdx.x / (NPIX / TQ);
    const int n0  = (blockIdx.x % (NPIX / TQ)) * TQ;

    const float* kqb = kq  + (size_t)b * CK  * NPIX;
    const float* vbp = val + (size_t)b * CVC * NPIX;

    // stage Q tile: Qs[q][c] = kq[b, c, n0+q]   (coalesced 32-wide segments)
    #pragma unroll
    for (int i = 0; i < (TQ * CK) / 256; ++i) {
        int e = tid + i * 256;
        int q = e & (TQ - 1), c = e >> 5;
        Qs[q][c] = kqb[(size_t)c * NPIX + n0 + q];
    }
    if (tid < TQ) { mrow[tid] = -1e30f; lrow[tid] = 0.f; }

    const int qi  = (tid & 15) * 2;       // 2 query rows owned per thread
    const int mi  = (tid >> 4) * 2;       // 2 key cols in S phase
    const int cvb = (tid >> 4) * 16;      // 16 value channels in PV phase
    float acc0[16], acc1[16];
    #pragma unroll
    for (int j = 0; j < 16; ++j) { acc0[j] = 0.f; acc1[j] = 0.f; }

    for (int m0 = 0; m0 < NPIX; m0 += TK) {
        // stage K chunk: Ks[m][c] = kq[b, c, m0+m]
        #pragma unroll
        for (int i = 0; i < (TK * CK) / 256; ++i) {
            int e = tid + i * 256;
            int m = e & (TK - 1), c = e >> 5;
            Ks[m][c] = kqb[(size_t)c * NPIX + m0 + m];
        }
        // stage V chunk: Vs[m][cv] = value[b, cv, m0+m]
        #pragma unroll
        for (int i = 0; i < (TK * CVC) / 256; ++i) {
            int e = tid + i * 256;
            int m = e & (TK - 1), cv = e >> 5;
            Vs[m][cv] = vbp[(size_t)cv * NPIX + m0 + m];
        }
        __syncthreads();

        // S = Q^T K  (2x2 micro-tile per thread, float4 LDS reads)
        float s00 = 0.f, s01 = 0.f, s10 = 0.f, s11 = 0.f;
        {
            const float4* q0p = (const float4*)Qs[qi];
            const float4* q1p = (const float4*)Qs[qi + 1];
            const float4* k0p = (const float4*)Ks[mi];
            const float4* k1p = (const float4*)Ks[mi + 1];
            #pragma unroll 4
            for (int c4 = 0; c4 < CK / 4; ++c4) {
                float4 a0 = q0p[c4], a1 = q1p[c4];
                float4 b0 = k0p[c4], b1 = k1p[c4];
                s00 = fmaf(a0.x,b0.x, fmaf(a0.y,b0.y, fmaf(a0.z,b0.z, fmaf(a0.w,b0.w, s00))));
                s01 = fmaf(a0.x,b1.x, fmaf(a0.y,b1.y, fmaf(a0.z,b1.z, fmaf(a0.w,b1.w, s01))));
                s10 = fmaf(a1.x,b0.x, fmaf(a1.y,b0.y, fmaf(a1.z,b0.z, fmaf(a1.w,b0.w, s10))));
                s11 = fmaf(a1.x,b1.x, fmaf(a1.y,b1.y, fmaf(a1.z,b1.z, fmaf(a1.w,b1.w, s11))));
            }
        }
        Ps[qi][mi] = s00;  Ps[qi][mi+1] = s01;
        Ps[qi+1][mi] = s10; Ps[qi+1][mi+1] = s11;
        __syncthreads();

        // online softmax: 8 lanes per query row (rows stay within one wave)
        {
            int q = tid >> 3;
            int j = tid & 7;
            float s0 = Ps[q][j*4+0], s1 = Ps[q][j*4+1];
            float s2 = Ps[q][j*4+2], s3 = Ps[q][j*4+3];
            float cmax = fmaxf(fmaxf(s0, s1), fmaxf(s2, s3));
            #pragma unroll
            for (int off = 1; off < 8; off <<= 1)
                cmax = fmaxf(cmax, __shfl_xor(cmax, off, 8));
            float mold = mrow[q];
            float mnew = fmaxf(mold, cmax);
            float alpha = __expf(mold - mnew);
            float p0 = __expf(s0 - mnew), p1 = __expf(s1 - mnew);
            float p2 = __expf(s2 - mnew), p3 = __expf(s3 - mnew);
            Ps[q][j*4+0] = p0; Ps[q][j*4+1] = p1;
            Ps[q][j*4+2] = p2; Ps[q][j*4+3] = p3;
            float rsum = p0 + p1 + p2 + p3;
            #pragma unroll
            for (int off = 1; off < 8; off <<= 1)
                rsum += __shfl_xor(rsum, off, 8);
            if (j == 0) {
                mrow[q] = mnew;
                lrow[q] = lrow[q] * alpha + rsum;
                arow[q] = alpha;
            }
        }
        __syncthreads();

        // PV: acc[q][cv] = acc*alpha + P @ V  (2q x 16cv per thread)
        {
            float a0 = arow[qi], a1 = arow[qi + 1];
            #pragma unroll
            for (int j = 0; j < 16; ++j) { acc0[j] *= a0; acc1[j] *= a1; }
            #pragma unroll 4
            for (int m = 0; m < TK; ++m) {
                float p0 = Ps[qi][m], p1 = Ps[qi + 1][m];
                const float4* vp = (const float4*)&Vs[m][cvb];
                #pragma unroll
                for (int k = 0; k < 4; ++k) {
                    float4 v = vp[k];
                    acc0[4*k+0] = fmaf(p0, v.x, acc0[4*k+0]);
                    acc0[4*k+1] = fmaf(p0, v.y, acc0[4*k+1]);
                    acc0[4*k+2] = fmaf(p0, v.z, acc0[4*k+2]);
                    acc0[4*k+3] = fmaf(p0, v.w, acc0[4*k+3]);
                    acc1[4*k+0] = fmaf(p1, v.x, acc1[4*k+0]);
                    acc1[4*k+1] = fmaf(p1, v.y, acc1[4*k+1]);
                    acc1[4*k+2] = fmaf(p1, v.z, acc1[4*k+2]);
                    acc1[4*k+3] = fmaf(p1, v.w, acc1[4*k+3]);
                }
            }
        }
        __syncthreads();
    }

    // epilogue: normalize and store ctx[b, cv, n0+q]
    float linv0 = 1.f / lrow[qi], linv1 = 1.f / lrow[qi + 1];
    float* cb = ctx + (size_t)b * CVC * NPIX + n0;
    #pragma unroll
    for (int j = 0; j < 16; ++j) {
        cb[(size_t)(cvb + j) * NPIX + qi]     = acc0[j] * linv0;
        cb[(size_t)(cvb + j) * NPIX + qi + 1] = acc1[j] * linv1;
    }
}

// ---------------- out = 1x1 conv(ctx) + x ----------------
__global__ void out_kernel(const float* __restrict__ ctx, const float* __restrict__ ww,
                           const float* __restrict__ bw, const float* __restrict__ x,
                           float* __restrict__ out)
{
    int idx = blockIdx.x * 256 + threadIdx.x;          // b*COUTC*NPIX + co*NPIX + n
    if (idx >= NB * COUTC * NPIX) return;
    int n  = idx % NPIX;
    int co = (idx / NPIX) % COUTC;
    int b  = idx / (NPIX * COUTC);
    const float* cp = ctx + (size_t)b * CVC * NPIX + n;
    const float* wp = ww + co * CVC;
    float acc = bw[co];
    #pragma unroll 8
    for (int cv = 0; cv < CVC; ++cv)
        acc = fmaf(wp[cv], cp[(size_t)cv * NPIX], acc);
    out[idx] = acc + x[idx];
}

extern "C" void kernel_launch(void* const* d_in, const int* in_sizes, int n_in,
                              void* d_out, int out_size, void* d_ws, size_t ws_size,
                              hipStream_t stream)
{
    const float* x     = (const float*)d_in[0];
    const float* wk    = (const float*)d_in[1];
    const float* bk    = (const float*)d_in[2];
    const float* gamma = (const float*)d_in[3];
    const float* beta  = (const float*)d_in[4];
    const float* rmean = (const float*)d_in[5];
    const float* rvar  = (const float*)d_in[6];
    const float* wv    = (const float*)d_in[7];
    const float* bv    = (const float*)d_in[8];
    const float* ww    = (const float*)d_in[9];
    const float* bw    = (const float*)d_in[10];
    float* out = (float*)d_out;

    // workspace: kq [B,CK,N] | value [B,CVC,N] | ctx [B,CVC,N]  = 32.8 MB total
    float* kqbuf = (float*)d_ws;
    float* vbuf  = kqbuf + (size_t)NB * CK  * NPIX;
    float* cbuf  = vbuf  + (size_t)NB * CVC * NPIX;

    kq_kernel   <<<(NB * CK   * NPIX) / 256, 256, 0, stream>>>(x, wk, bk, gamma, beta, rmean, rvar, kqbuf);
    conv3_kernel<<<(NB * CVC  * NPIX) / 256, 256, 0, stream>>>(x, wv, bv, vbuf);
    attn_kernel <<<NB * (NPIX / TQ),         256, 0, stream>>>(kqbuf, vbuf, cbuf);
    out_kernel  <<<(NB * COUTC * NPIX) / 256, 256, 0, stream>>>(cbuf, ww, bw, x, out);
}

// Round 2
// 814.801 us; speedup vs baseline: 5.9520x; 5.9520x over previous
//
#include <hip/hip_runtime.h>
#include <math.h>

// Problem constants (fixed by setup_inputs)
#define NB   2
#define CIN  256
#define IMH  80
#define IMW  80
#define NPIX (IMH*IMW)   // 6400
#define CK   128
#define CVC  256
#define COUTC 256
#define BN_EPS 1e-5f

typedef short sx8 __attribute__((ext_vector_type(8)));    // 8 bf16 in 4 VGPRs
typedef float f32x4 __attribute__((ext_vector_type(4)));

__device__ __forceinline__ short f2bf(float f) {
    unsigned u = __builtin_bit_cast(unsigned, f);
    u += 0x7fffu + ((u >> 16) & 1u);   // RNE
    return (short)(u >> 16);
}

// ---------------- kq = BN(1x1 conv(x)) ; bf16 [B, CK, N] ----------------
// grid: (NPIX/256, CK/8, NB)
__global__ __launch_bounds__(256) void kq_kernel(
    const float* __restrict__ x, const float* __restrict__ wk,
    const float* __restrict__ bk, const float* __restrict__ gamma,
    const float* __restrict__ beta, const float* __restrict__ rmean,
    const float* __restrict__ rvar, short* __restrict__ kq)
{
    int n  = blockIdx.x * 256 + threadIdx.x;
    int c0 = blockIdx.y * 8;
    int b  = blockIdx.z;
    const float* xp = x + (size_t)b * CIN * NPIX + n;
    float acc[8] = {0,0,0,0,0,0,0,0};
    for (int c = 0; c < CIN; ++c) {
        float xv = xp[(size_t)c * NPIX];
        #pragma unroll
        for (int k = 0; k < 8; ++k)
            acc[k] = fmaf(wk[(c0 + k) * CIN + c], xv, acc[k]);
    }
    #pragma unroll
    for (int k = 0; k < 8; ++k) {
        int ck = c0 + k;
        float inv = gamma[ck] * rsqrtf(rvar[ck] + BN_EPS);
        float v = (acc[k] + bk[ck]) * inv + (beta[ck] - rmean[ck] * inv);
        kq[((size_t)b * CK + ck) * NPIX + n] = f2bf(v);
    }
}

// ---------------- value = 3x3 conv(x), pad 1 ; bf16 [B, CVC, N] ----------------
// grid: (NPIX/256, CVC/8, NB)
__global__ __launch_bounds__(256) void conv3_kernel(
    const float* __restrict__ x, const float* __restrict__ wv,
    const float* __restrict__ bv, short* __restrict__ val)
{
    int n   = blockIdx.x * 256 + threadIdx.x;
    int cv0 = blockIdx.y * 8;
    int b   = blockIdx.z;
    int h = n / IMW, w = n % IMW;
    bool hu = (h > 0), hd = (h < IMH-1), wl = (w > 0), wr = (w < IMW-1);
    const float* xb = x + (size_t)b * CIN * NPIX;

    float acc[8];
    #pragma unroll
    for (int k = 0; k < 8; ++k) acc[k] = bv[cv0 + k];

    for (int c = 0; c < CIN; ++c) {
        const float* xc = xb + (size_t)c * NPIX + n;
        float x0 = (hu && wl) ? xc[-IMW-1] : 0.f;
        float x1 =  hu        ? xc[-IMW  ] : 0.f;
        float x2 = (hu && wr) ? xc[-IMW+1] : 0.f;
        float x3 =  wl        ? xc[-1]     : 0.f;
        float x4 =              xc[0];
        float x5 =  wr        ? xc[1]      : 0.f;
        float x6 = (hd && wl) ? xc[ IMW-1] : 0.f;
        float x7 =  hd        ? xc[ IMW  ] : 0.f;
        float x8 = (hd && wr) ? xc[ IMW+1] : 0.f;
        #pragma unroll
        for (int k = 0; k < 8; ++k) {
            const float* wp = wv + ((size_t)(cv0 + k) * CIN + c) * 9;  // wave-uniform -> s_load
            acc[k] = fmaf(wp[0], x0, acc[k]);
            acc[k] = fmaf(wp[1], x1, acc[k]);
            acc[k] = fmaf(wp[2], x2, acc[k]);
            acc[k] = fmaf(wp[3], x3, acc[k]);
            acc[k] = fmaf(wp[4], x4, acc[k]);
            acc[k] = fmaf(wp[5], x5, acc[k]);
            acc[k] = fmaf(wp[6], x6, acc[k]);
            acc[k] = fmaf(wp[7], x7, acc[k]);
            acc[k] = fmaf(wp[8], x8, acc[k]);
        }
    }
    #pragma unroll
    for (int k = 0; k < 8; ++k)
        val[((size_t)b * CVC + cv0 + k) * NPIX + n] = f2bf(acc[k]);
}

// ---------------- MFMA flash attention: ctx[b,cv,n] = softmax(kq^T kq) @ value^T ----------------
#define TQ 64
#define TK 64
#define KS_LD 136   // bf16 elems/row: 272 B -> bank stride 4, 2-way on frag reads (free)
#define VS_LD 72    // 144 B -> bank stride 4
#define PS_LD 72

__global__ __launch_bounds__(256) void attn_kernel(
    const short* __restrict__ kq, const short* __restrict__ val,
    float* __restrict__ ctx)
{
    __shared__ __align__(16) short Ks[TK][KS_LD];     // 17408 B (also Q staging)
    __shared__ __align__(16) short Vs[CVC][VS_LD];    // 36864 B
    __shared__ __align__(16) short Ps[TQ][PS_LD];     // 9216 B (P in bf16)
    __shared__ float arow[TQ];
    __shared__ float lrow[TQ];

    const int tid  = threadIdx.x;
    const int wid  = tid >> 6;       // wave 0..3
    const int lane = tid & 63;
    const int l15  = lane & 15;
    const int quad = lane >> 4;

    const int b  = blockIdx.x / (NPIX / TQ);
    const int n0 = (blockIdx.x % (NPIX / TQ)) * TQ;

    const short* kqb = kq  + (size_t)b * CK  * NPIX;
    const short* vb  = val + (size_t)b * CVC * NPIX;

    // ---- stage Q tile (transpose): Ks[q][c] = kq[c][n0+q], then keep frags in regs
    {
        int m = tid & 63, cg = tid >> 6;
        #pragma unroll
        for (int p = 0; p < 4; ++p) {
            int c8 = (cg + p * 4) * 8;
            sx8 t;
            #pragma unroll
            for (int j = 0; j < 8; ++j)
                t[j] = kqb[(size_t)(c8 + j) * NPIX + n0 + m];
            *(sx8*)&Ks[m][c8] = t;
        }
    }
    __syncthreads();

    sx8 qf[4];   // A-operand: A[m=l15][k=quad*8+j], k-slabs of 32 over CK=128
    #pragma unroll
    for (int s = 0; s < 4; ++s)
        qf[s] = *(const sx8*)&Ks[wid * 16 + l15][s * 32 + quad * 8];

    float mrun[4], lsum[4];
    #pragma unroll
    for (int r = 0; r < 4; ++r) { mrun[r] = -1e30f; lsum[r] = 0.f; }

    f32x4 acc[4][4];   // [q-tile][cv-tile]; D row=quad*4+reg, col=l15
    #pragma unroll
    for (int qt = 0; qt < 4; ++qt)
        #pragma unroll
        for (int ct = 0; ct < 4; ++ct)
            acc[qt][ct] = (f32x4){0.f, 0.f, 0.f, 0.f};

    for (int m0 = 0; m0 < NPIX; m0 += TK) {
        __syncthreads();   // prev-iter readers of Ks/Vs/Ps done
        // stage K chunk (transpose): Ks[m][c]
        {
            int m = tid & 63, cg = tid >> 6;
            #pragma unroll
            for (int p = 0; p < 4; ++p) {
                int c8 = (cg + p * 4) * 8;
                sx8 t;
                #pragma unroll
                for (int j = 0; j < 8; ++j)
                    t[j] = kqb[(size_t)(c8 + j) * NPIX + m0 + m];
                *(sx8*)&Ks[m][c8] = t;
            }
        }
        // stage V chunk (no transpose): Vs[cv][m]
        {
            int m8 = (tid & 7) * 8, cvo = tid >> 3;
            #pragma unroll
            for (int p = 0; p < 8; ++p) {
                int cv = cvo + p * 32;
                *(sx8*)&Vs[cv][m8] = *(const sx8*)&vb[(size_t)cv * NPIX + m0 + m8];
            }
        }
        __syncthreads();

        // ---- S phase: this wave computes S[16 q][64 m], q = n0+wid*16+row
        f32x4 st[4];
        #pragma unroll
        for (int t = 0; t < 4; ++t) {
            f32x4 d = (f32x4){0.f, 0.f, 0.f, 0.f};
            #pragma unroll
            for (int s = 0; s < 4; ++s) {
                sx8 bf = *(const sx8*)&Ks[t * 16 + l15][s * 32 + quad * 8];
                d = __builtin_amdgcn_mfma_f32_16x16x32_bf16(qf[s], bf, d, 0, 0, 0);
            }
            st[t] = d;
        }

        // ---- online softmax per row (row spread over 16 lanes of the quad)
        float al[4];
        #pragma unroll
        for (int r = 0; r < 4; ++r) {
            float rm = fmaxf(fmaxf(st[0][r], st[1][r]), fmaxf(st[2][r], st[3][r]));
            #pragma unroll
            for (int o = 1; o < 16; o <<= 1)
                rm = fmaxf(rm, __shfl_xor(rm, o, 16));
            float mnew = fmaxf(mrun[r], rm);
            al[r] = __expf(mrun[r] - mnew);
            mrun[r] = mnew;
            float p0 = __expf(st[0][r] - mnew), p1 = __expf(st[1][r] - mnew);
            float p2 = __expf(st[2][r] - mnew), p3 = __expf(st[3][r] - mnew);
            st[0][r] = p0; st[1][r] = p1; st[2][r] = p2; st[3][r] = p3;
            float rs = p0 + p1 + p2 + p3;
            #pragma unroll
            for (int o = 1; o < 16; o <<= 1)
                rs += __shfl_xor(rs, o, 16);
            lsum[r] = lsum[r] * al[r] + rs;
        }
        // write P (bf16, C-layout -> LDS) and alpha
        #pragma unroll
        for (int t = 0; t < 4; ++t)
            #pragma unroll
            for (int r = 0; r < 4; ++r)
                Ps[wid * 16 + quad * 4 + r][t * 16 + l15] = f2bf(st[t][r]);
        if (l15 == 0) {
            #pragma unroll
            for (int r = 0; r < 4; ++r)
                arow[wid * 16 + quad * 4 + r] = al[r];
        }
        __syncthreads();

        // ---- PV phase: this wave covers cv in [wid*64, wid*64+64), all 64 q
        #pragma unroll
        for (int qt = 0; qt < 4; ++qt) {
            f32x4 a4 = *(const f32x4*)&arow[qt * 16 + quad * 4];
            #pragma unroll
            for (int ct = 0; ct < 4; ++ct)
                acc[qt][ct] *= a4;
        }
        #pragma unroll
        for (int s = 0; s < 2; ++s) {
            sx8 pa[4];   // A-operand: P[q=l15][k=key]
            #pragma unroll
            for (int qt = 0; qt < 4; ++qt)
                pa[qt] = *(const sx8*)&Ps[qt * 16 + l15][s * 32 + quad * 8];
            #pragma unroll
            for (int ct = 0; ct < 4; ++ct) {
                sx8 vf = *(const sx8*)&Vs[wid * 64 + ct * 16 + l15][s * 32 + quad * 8];
                #pragma unroll
                for (int qt = 0; qt < 4; ++qt)
                    acc[qt][ct] = __builtin_amdgcn_mfma_f32_16x16x32_bf16(pa[qt], vf, acc[qt][ct], 0, 0, 0);
            }
        }
    }

    if (l15 == 0) {
        #pragma unroll
        for (int r = 0; r < 4; ++r)
            lrow[wid * 16 + quad * 4 + r] = lsum[r];
    }
    __syncthreads();

    // ---- epilogue: ctx[b, cv, n0+q] fp32; float4 along q (rows quad*4..+3 contiguous)
    #pragma unroll
    for (int qt = 0; qt < 4; ++qt) {
        f32x4 lv = *(const f32x4*)&lrow[qt * 16 + quad * 4];
        f32x4 inv;
        #pragma unroll
        for (int r = 0; r < 4; ++r) inv[r] = 1.0f / lv[r];
        #pragma unroll
        for (int ct = 0; ct < 4; ++ct) {
            int cv = wid * 64 + ct * 16 + l15;
            f32x4 o = acc[qt][ct] * inv;
            *(f32x4*)&ctx[((size_t)b * CVC + cv) * NPIX + n0 + qt * 16 + quad * 4] = o;
        }
    }
}

// ---------------- out = 1x1 conv(ctx) + x ----------------
// grid: (NPIX/256, COUTC/8, NB)
__global__ __launch_bounds__(256) void out_kernel(
    const float* __restrict__ ctx, const float* __restrict__ ww,
    const float* __restrict__ bw, const float* __restrict__ x,
    float* __restrict__ out)
{
    int n   = blockIdx.x * 256 + threadIdx.x;
    int co0 = blockIdx.y * 8;
    int b   = blockIdx.z;
    const float* cp = ctx + (size_t)b * CVC * NPIX + n;
    float acc[8];
    #pragma unroll
    for (int k = 0; k < 8; ++k) acc[k] = bw[co0 + k];
    for (int cv = 0; cv < CVC; ++cv) {
        float cval = cp[(size_t)cv * NPIX];
        #pragma unroll
        for (int k = 0; k < 8; ++k)
            acc[k] = fmaf(ww[(size_t)(co0 + k) * CVC + cv], cval, acc[k]);
    }
    #pragma unroll
    for (int k = 0; k < 8; ++k) {
        size_t idx = ((size_t)b * COUTC + co0 + k) * NPIX + n;
        out[idx] = acc[k] + x[idx];
    }
}

extern "C" void kernel_launch(void* const* d_in, const int* in_sizes, int n_in,
                              void* d_out, int out_size, void* d_ws, size_t ws_size,
                              hipStream_t stream)
{
    const float* x     = (const float*)d_in[0];
    const float* wk    = (const float*)d_in[1];
    const float* bk    = (const float*)d_in[2];
    const float* gamma = (const float*)d_in[3];
    const float* beta  = (const float*)d_in[4];
    const float* rmean = (const float*)d_in[5];
    const float* rvar  = (const float*)d_in[6];
    const float* wv    = (const float*)d_in[7];
    const float* bv    = (const float*)d_in[8];
    const float* ww    = (const float*)d_in[9];
    const float* bw    = (const float*)d_in[10];
    float* out = (float*)d_out;

    // ws: kq bf16 [B,CK,N] | value bf16 [B,CVC,N] | ctx fp32 [B,CVC,N]  (~23 MB)
    short* kqbuf = (short*)d_ws;
    short* vbuf  = kqbuf + (size_t)NB * CK * NPIX;
    float* cbuf  = (float*)(vbuf + (size_t)NB * CVC * NPIX);

    kq_kernel   <<<dim3(NPIX/256, CK/8,    NB), 256, 0, stream>>>(x, wk, bk, gamma, beta, rmean, rvar, kqbuf);
    conv3_kernel<<<dim3(NPIX/256, CVC/8,   NB), 256, 0, stream>>>(x, wv, bv, vbuf);
    attn_kernel <<<NB * (NPIX / TQ),            256, 0, stream>>>(kqbuf, vbuf, cbuf);
    out_kernel  <<<dim3(NPIX/256, COUTC/8, NB), 256, 0, stream>>>(cbuf, ww, bw, x, out);
}

// Round 3
// 516.820 us; speedup vs baseline: 9.3837x; 1.5766x over previous
//
#include <hip/hip_runtime.h>
#include <math.h>

// Problem constants (fixed by setup_inputs)
#define NB   2
#define CIN  256
#define IMH  80
#define IMW  80
#define NPIX (IMH*IMW)   // 6400
#define CK   128
#define CVC  256
#define COUTC 256
#define BN_EPS 1e-5f
#define HP   82          // padded H/W (NHWC bf16 xpad)
#define WP   82

typedef short sx8 __attribute__((ext_vector_type(8)));    // 8 bf16 in 4 VGPRs
typedef float f32x4 __attribute__((ext_vector_type(4)));

__device__ __forceinline__ short f2bf(float f) {
    unsigned u = __builtin_bit_cast(unsigned, f);
    u += 0x7fffu + ((u >> 16) & 1u);   // RNE
    return (short)(u >> 16);
}

// ---------------- xpad: NCHW fp32 -> NHWC-padded bf16 [B][82][82][256] ----------------
// grid: (NPIX/64, NB), block 256.  Borders must be pre-zeroed (hipMemsetAsync).
__global__ __launch_bounds__(256) void pad_kernel(const float* __restrict__ x,
                                                  short* __restrict__ xpad)
{
    __shared__ short T[64][258];   // 33 KB; stride 258 shorts = 129 dw -> conflict-free
    const int tid = threadIdx.x;
    const int n0  = blockIdx.x * 64;
    const int b   = blockIdx.y;
    const float* xb = x + (size_t)b * CIN * NPIX;

    #pragma unroll
    for (int i = 0; i < 16; ++i) {
        int e = tid + i * 256;          // 4096 elems: 64 pix x 64 c per pass... x4 passes folded
        int pix = e & 63, c = e >> 6;   // c in 0..63 here; cover 256 via 4 strided groups
        #pragma unroll
        for (int g = 0; g < 4; ++g) {
            if (i < 4) { }              // (nop to keep structure simple)
        }
        (void)pix; (void)c;
        break;
    }
    // simpler explicit version: 256 channels x 64 pixels = 16384 elems, 64 iters
    #pragma unroll 4
    for (int i = 0; i < 64; ++i) {
        int e = tid + i * 256;
        int pix = e & 63, c = e >> 6;
        T[pix][c] = f2bf(xb[(size_t)c * NPIX + n0 + pix]);
    }
    __syncthreads();
    // write out: each pixel's 256 channels are contiguous (512 B)
    #pragma unroll
    for (int i = 0; i < 8; ++i) {
        int e   = tid + i * 256;
        int pix = e >> 5;
        int cp  = (e & 31) * 8;
        int np  = n0 + pix;
        int hp  = np / IMW + 1, wp = np % IMW + 1;
        sx8 v = *(const sx8*)&T[pix][cp];
        *(sx8*)&xpad[(((size_t)b * HP + hp) * WP + wp) * CIN + cp] = v;
    }
}

// ---------------- wv [256][256][3][3] fp32 -> wv_t [9][256][256] bf16 ----------------
__global__ __launch_bounds__(256) void wvt_kernel(const float* __restrict__ wv,
                                                  short* __restrict__ wvt)
{
    int idx = blockIdx.x * 256 + threadIdx.x;   // over [9][256][256]
    int tap = idx >> 16;
    int cv  = (idx >> 8) & 255;
    int c   = idx & 255;
    wvt[idx] = f2bf(wv[((size_t)cv * CIN + c) * 9 + tap]);
}

// ---------------- kq = BN(1x1 conv(x)) ; bf16 [B, CK, N] ----------------
// grid: (NPIX/256, CK/8, NB)
__global__ __launch_bounds__(256) void kq_kernel(
    const float* __restrict__ x, const float* __restrict__ wk,
    const float* __restrict__ bk, const float* __restrict__ gamma,
    const float* __restrict__ beta, const float* __restrict__ rmean,
    const float* __restrict__ rvar, short* __restrict__ kq)
{
    int n  = blockIdx.x * 256 + threadIdx.x;
    int c0 = blockIdx.y * 8;
    int b  = blockIdx.z;
    const float* xp = x + (size_t)b * CIN * NPIX + n;
    float acc[8] = {0,0,0,0,0,0,0,0};
    for (int c = 0; c < CIN; ++c) {
        float xv = xp[(size_t)c * NPIX];
        #pragma unroll
        for (int k = 0; k < 8; ++k)
            acc[k] = fmaf(wk[(c0 + k) * CIN + c], xv, acc[k]);
    }
    #pragma unroll
    for (int k = 0; k < 8; ++k) {
        int ck = c0 + k;
        float inv = gamma[ck] * rsqrtf(rvar[ck] + BN_EPS);
        float v = (acc[k] + bk[ck]) * inv + (beta[ck] - rmean[ck] * inv);
        kq[((size_t)b * CK + ck) * NPIX + n] = f2bf(v);
    }
}

// ---------------- value = 3x3 conv via MFMA implicit GEMM ; bf16 [B, CVC, N] ----------------
// grid: (100 tiles, CVC/64, NB), block 256 (4 waves; wave = 16-cv m-sub)
#define CSTRIDE 36   // shorts; col stride 72 B -> uniform 8-way b128 (minimum)
__global__ __launch_bounds__(256) void conv3_kernel(
    const short* __restrict__ xpad, const short* __restrict__ wvt,
    const float* __restrict__ bv, short* __restrict__ val)
{
    __shared__ __align__(16) short Xs[6 * 18 * CSTRIDE];   // 7776 B

    const int tid  = threadIdx.x;
    const int wid  = tid >> 6;
    const int lane = tid & 63;
    const int l15  = lane & 15;
    const int quad = lane >> 4;

    const int rowT = blockIdx.x / 5, colT = blockIdx.x % 5;
    const int h0 = rowT * 4, w0 = colT * 16;
    const int cv0 = blockIdx.y * 64 + wid * 16;
    const int b   = blockIdx.z;

    const short* xb = xpad + (size_t)b * HP * WP * CIN;

    f32x4 acc[4];
    #pragma unroll
    for (int r = 0; r < 4; ++r) acc[r] = (f32x4){0.f, 0.f, 0.f, 0.f};

    for (int cc = 0; cc < CIN / 32; ++cc) {
        __syncthreads();
        // stage 6 rows x 18 cols x 32 channels (bf16) into LDS
        #pragma unroll
        for (int i = 0; i < 2; ++i) {
            int e = tid + i * 256;
            if (e < 432) {
                int rc = e >> 2, l4 = e & 3;
                int row = rc / 18, col = rc % 18;
                sx8 v = *(const sx8*)&xb[(((size_t)(h0 + row)) * WP + (w0 + col)) * CIN + cc * 32 + l4 * 8];
                *(sx8*)&Xs[rc * CSTRIDE + l4 * 8] = v;
            }
        }
        __syncthreads();

        #pragma unroll
        for (int dw = 0; dw < 3; ++dw) {
            sx8 Bf[6];
            #pragma unroll
            for (int rr = 0; rr < 6; ++rr)
                Bf[rr] = *(const sx8*)&Xs[(rr * 18 + l15 + dw) * CSTRIDE + quad * 8];
            #pragma unroll
            for (int dh = 0; dh < 3; ++dh) {
                int tap = dh * 3 + dw;
                sx8 Af = *(const sx8*)&wvt[((size_t)(tap * 256 + cv0 + l15)) * CIN + cc * 32 + quad * 8];
                #pragma unroll
                for (int r = 0; r < 4; ++r)
                    acc[r] = __builtin_amdgcn_mfma_f32_16x16x32_bf16(Af, Bf[r + dh], acc[r], 0, 0, 0);
            }
        }
    }

    // store: D row (quad*4+reg) = cv, col (l15) = pixel
    f32x4 bvv = *(const f32x4*)&bv[cv0 + quad * 4];
    #pragma unroll
    for (int r = 0; r < 4; ++r) {
        int n = (h0 + r) * IMW + w0 + l15;
        #pragma unroll
        for (int reg = 0; reg < 4; ++reg) {
            int cv = cv0 + quad * 4 + reg;
            val[((size_t)b * CVC + cv) * NPIX + n] = f2bf(acc[r][reg] + bvv[reg]);
        }
    }
}

// ---------------- MFMA flash attention: ctx[b,cv,n] = softmax(kq^T kq) @ value^T ----------------
#define TQ 64
#define TK 64
#define KS_LD 136
#define VS_LD 72
#define PS_LD 72

__global__ __launch_bounds__(256) void attn_kernel(
    const short* __restrict__ kq, const short* __restrict__ val,
    float* __restrict__ ctx)
{
    __shared__ __align__(16) short Ks[TK][KS_LD];
    __shared__ __align__(16) short Vs[CVC][VS_LD];
    __shared__ __align__(16) short Ps[TQ][PS_LD];
    __shared__ float arow[TQ];
    __shared__ float lrow[TQ];

    const int tid  = threadIdx.x;
    const int wid  = tid >> 6;
    const int lane = tid & 63;
    const int l15  = lane & 15;
    const int quad = lane >> 4;

    const int b  = blockIdx.x / (NPIX / TQ);
    const int n0 = (blockIdx.x % (NPIX / TQ)) * TQ;

    const short* kqb = kq  + (size_t)b * CK  * NPIX;
    const short* vb  = val + (size_t)b * CVC * NPIX;

    {
        int m = tid & 63, cg = tid >> 6;
        #pragma unroll
        for (int p = 0; p < 4; ++p) {
            int c8 = (cg + p * 4) * 8;
            sx8 t;
            #pragma unroll
            for (int j = 0; j < 8; ++j)
                t[j] = kqb[(size_t)(c8 + j) * NPIX + n0 + m];
            *(sx8*)&Ks[m][c8] = t;
        }
    }
    __syncthreads();

    sx8 qf[4];
    #pragma unroll
    for (int s = 0; s < 4; ++s)
        qf[s] = *(const sx8*)&Ks[wid * 16 + l15][s * 32 + quad * 8];

    float mrun[4], lsum[4];
    #pragma unroll
    for (int r = 0; r < 4; ++r) { mrun[r] = -1e30f; lsum[r] = 0.f; }

    f32x4 acc[4][4];
    #pragma unroll
    for (int qt = 0; qt < 4; ++qt)
        #pragma unroll
        for (int ct = 0; ct < 4; ++ct)
            acc[qt][ct] = (f32x4){0.f, 0.f, 0.f, 0.f};

    for (int m0 = 0; m0 < NPIX; m0 += TK) {
        __syncthreads();
        {
            int m = tid & 63, cg = tid >> 6;
            #pragma unroll
            for (int p = 0; p < 4; ++p) {
                int c8 = (cg + p * 4) * 8;
                sx8 t;
                #pragma unroll
                for (int j = 0; j < 8; ++j)
                    t[j] = kqb[(size_t)(c8 + j) * NPIX + m0 + m];
                *(sx8*)&Ks[m][c8] = t;
            }
        }
        {
            int m8 = (tid & 7) * 8, cvo = tid >> 3;
            #pragma unroll
            for (int p = 0; p < 8; ++p) {
                int cv = cvo + p * 32;
                *(sx8*)&Vs[cv][m8] = *(const sx8*)&vb[(size_t)cv * NPIX + m0 + m8];
            }
        }
        __syncthreads();

        f32x4 st[4];
        #pragma unroll
        for (int t = 0; t < 4; ++t) {
            f32x4 d = (f32x4){0.f, 0.f, 0.f, 0.f};
            #pragma unroll
            for (int s = 0; s < 4; ++s) {
                sx8 bf = *(const sx8*)&Ks[t * 16 + l15][s * 32 + quad * 8];
                d = __builtin_amdgcn_mfma_f32_16x16x32_bf16(qf[s], bf, d, 0, 0, 0);
            }
            st[t] = d;
        }

        float al[4];
        #pragma unroll
        for (int r = 0; r < 4; ++r) {
            float rm = fmaxf(fmaxf(st[0][r], st[1][r]), fmaxf(st[2][r], st[3][r]));
            #pragma unroll
            for (int o = 1; o < 16; o <<= 1)
                rm = fmaxf(rm, __shfl_xor(rm, o, 16));
            float mnew = fmaxf(mrun[r], rm);
            al[r] = __expf(mrun[r] - mnew);
            mrun[r] = mnew;
            float p0 = __expf(st[0][r] - mnew), p1 = __expf(st[1][r] - mnew);
            float p2 = __expf(st[2][r] - mnew), p3 = __expf(st[3][r] - mnew);
            st[0][r] = p0; st[1][r] = p1; st[2][r] = p2; st[3][r] = p3;
            float rs = p0 + p1 + p2 + p3;
            #pragma unroll
            for (int o = 1; o < 16; o <<= 1)
                rs += __shfl_xor(rs, o, 16);
            lsum[r] = lsum[r] * al[r] + rs;
        }
        #pragma unroll
        for (int t = 0; t < 4; ++t)
            #pragma unroll
            for (int r = 0; r < 4; ++r)
                Ps[wid * 16 + quad * 4 + r][t * 16 + l15] = f2bf(st[t][r]);
        if (l15 == 0) {
            #pragma unroll
            for (int r = 0; r < 4; ++r)
                arow[wid * 16 + quad * 4 + r] = al[r];
        }
        __syncthreads();

        #pragma unroll
        for (int qt = 0; qt < 4; ++qt) {
            f32x4 a4 = *(const f32x4*)&arow[qt * 16 + quad * 4];
            #pragma unroll
            for (int ct = 0; ct < 4; ++ct)
                acc[qt][ct] *= a4;
        }
        #pragma unroll
        for (int s = 0; s < 2; ++s) {
            sx8 pa[4];
            #pragma unroll
            for (int qt = 0; qt < 4; ++qt)
                pa[qt] = *(const sx8*)&Ps[qt * 16 + l15][s * 32 + quad * 8];
            #pragma unroll
            for (int ct = 0; ct < 4; ++ct) {
                sx8 vf = *(const sx8*)&Vs[wid * 64 + ct * 16 + l15][s * 32 + quad * 8];
                #pragma unroll
                for (int qt = 0; qt < 4; ++qt)
                    acc[qt][ct] = __builtin_amdgcn_mfma_f32_16x16x32_bf16(pa[qt], vf, acc[qt][ct], 0, 0, 0);
            }
        }
    }

    if (l15 == 0) {
        #pragma unroll
        for (int r = 0; r < 4; ++r)
            lrow[wid * 16 + quad * 4 + r] = lsum[r];
    }
    __syncthreads();

    #pragma unroll
    for (int qt = 0; qt < 4; ++qt) {
        f32x4 lv = *(const f32x4*)&lrow[qt * 16 + quad * 4];
        f32x4 inv;
        #pragma unroll
        for (int r = 0; r < 4; ++r) inv[r] = 1.0f / lv[r];
        #pragma unroll
        for (int ct = 0; ct < 4; ++ct) {
            int cv = wid * 64 + ct * 16 + l15;
            f32x4 o = acc[qt][ct] * inv;
            *(f32x4*)&ctx[((size_t)b * CVC + cv) * NPIX + n0 + qt * 16 + quad * 4] = o;
        }
    }
}

// ---------------- out = 1x1 conv(ctx) + x ----------------
// grid: (NPIX/256, COUTC/8, NB)
__global__ __launch_bounds__(256) void out_kernel(
    const float* __restrict__ ctx, const float* __restrict__ ww,
    const float* __restrict__ bw, const float* __restrict__ x,
    float* __restrict__ out)
{
    int n   = blockIdx.x * 256 + threadIdx.x;
    int co0 = blockIdx.y * 8;
    int b   = blockIdx.z;
    const float* cp = ctx + (size_t)b * CVC * NPIX + n;
    float acc[8];
    #pragma unroll
    for (int k = 0; k < 8; ++k) acc[k] = bw[co0 + k];
    for (int cv = 0; cv < CVC; ++cv) {
        float cval = cp[(size_t)cv * NPIX];
        #pragma unroll
        for (int k = 0; k < 8; ++k)
            acc[k] = fmaf(ww[(size_t)(co0 + k) * CVC + cv], cval, acc[k]);
    }
    #pragma unroll
    for (int k = 0; k < 8; ++k) {
        size_t idx = ((size_t)b * COUTC + co0 + k) * NPIX + n;
        out[idx] = acc[k] + x[idx];
    }
}

extern "C" void kernel_launch(void* const* d_in, const int* in_sizes, int n_in,
                              void* d_out, int out_size, void* d_ws, size_t ws_size,
                              hipStream_t stream)
{
    const float* x     = (const float*)d_in[0];
    const float* wk    = (const float*)d_in[1];
    const float* bk    = (const float*)d_in[2];
    const float* gamma = (const float*)d_in[3];
    const float* beta  = (const float*)d_in[4];
    const float* rmean = (const float*)d_in[5];
    const float* rvar  = (const float*)d_in[6];
    const float* wv    = (const float*)d_in[7];
    const float* bv    = (const float*)d_in[8];
    const float* ww    = (const float*)d_in[9];
    const float* bw    = (const float*)d_in[10];
    float* out = (float*)d_out;

    // ws: xpad bf16 [B,82,82,256] | wvt bf16 [9,256,256] | kq bf16 | val bf16 | ctx fp32  (~31 MB)
    short* xpad  = (short*)d_ws;
    short* wvt   = xpad + (size_t)NB * HP * WP * CIN;
    short* kqbuf = wvt  + (size_t)9 * CVC * CIN;
    short* vbuf  = kqbuf + (size_t)NB * CK * NPIX;
    float* cbuf  = (float*)(vbuf + (size_t)NB * CVC * NPIX);

    hipMemsetAsync(xpad, 0, (size_t)NB * HP * WP * CIN * sizeof(short), stream);

    pad_kernel  <<<dim3(NPIX/64, NB),           256, 0, stream>>>(x, xpad);
    wvt_kernel  <<<(9*CVC*CIN)/256,             256, 0, stream>>>(wv, wvt);
    kq_kernel   <<<dim3(NPIX/256, CK/8,    NB), 256, 0, stream>>>(x, wk, bk, gamma, beta, rmean, rvar, kqbuf);
    conv3_kernel<<<dim3(100, CVC/64,       NB), 256, 0, stream>>>(xpad, wvt, bv, vbuf);
    attn_kernel <<<NB * (NPIX / TQ),            256, 0, stream>>>(kqbuf, vbuf, cbuf);
    out_kernel  <<<dim3(NPIX/256, COUTC/8, NB), 256, 0, stream>>>(cbuf, ww, bw, x, out);
}

// Round 4
// 418.242 us; speedup vs baseline: 11.5954x; 1.2357x over previous
//
#include <hip/hip_runtime.h>
#include <math.h>

// Problem constants (fixed by setup_inputs)
#define NB   2
#define CIN  256
#define IMH  80
#define IMW  80
#define NPIX (IMH*IMW)   // 6400
#define CK   128
#define CVC  256
#define COUTC 256
#define BN_EPS 1e-5f
#define HP   82          // padded H/W (NHWC bf16 xpad)
#define WP   82

typedef short sx8 __attribute__((ext_vector_type(8)));    // 8 bf16 in 4 VGPRs
typedef short sx4 __attribute__((ext_vector_type(4)));    // 4 bf16 in 2 VGPRs
typedef float f32x4 __attribute__((ext_vector_type(4)));

__device__ __forceinline__ short f2bf(float f) {
    unsigned u = __builtin_bit_cast(unsigned, f);
    u += 0x7fffu + ((u >> 16) & 1u);   // RNE
    return (short)(u >> 16);
}

// ---------------- xpad: NCHW fp32 -> NHWC-padded bf16 [B][82][82][256] ----------------
__global__ __launch_bounds__(256) void pad_kernel(const float* __restrict__ x,
                                                  short* __restrict__ xpad)
{
    __shared__ short T[64][258];
    const int tid = threadIdx.x;
    const int n0  = blockIdx.x * 64;
    const int b   = blockIdx.y;
    const float* xb = x + (size_t)b * CIN * NPIX;

    #pragma unroll 4
    for (int i = 0; i < 64; ++i) {
        int e = tid + i * 256;
        int pix = e & 63, c = e >> 6;
        T[pix][c] = f2bf(xb[(size_t)c * NPIX + n0 + pix]);
    }
    __syncthreads();
    #pragma unroll
    for (int i = 0; i < 8; ++i) {
        int e   = tid + i * 256;
        int pix = e >> 5;
        int cp  = (e & 31) * 8;
        int np  = n0 + pix;
        int hp  = np / IMW + 1, wp = np % IMW + 1;
        sx8 v = *(const sx8*)&T[pix][cp];
        *(sx8*)&xpad[(((size_t)b * HP + hp) * WP + wp) * CIN + cp] = v;
    }
}

// ---------------- wv [256][256][3][3] fp32 -> wv_t [9][256][256] bf16 ----------------
__global__ __launch_bounds__(256) void wvt_kernel(const float* __restrict__ wv,
                                                  short* __restrict__ wvt)
{
    int idx = blockIdx.x * 256 + threadIdx.x;
    int tap = idx >> 16;
    int cv  = (idx >> 8) & 255;
    int c   = idx & 255;
    wvt[idx] = f2bf(wv[((size_t)cv * CIN + c) * 9 + tap]);
}

// ---------------- ww [256][256] fp32 -> bf16 ----------------
__global__ __launch_bounds__(256) void wwb_kernel(const float* __restrict__ ww,
                                                  short* __restrict__ wwb)
{
    int idx = blockIdx.x * 256 + threadIdx.x;
    wwb[idx] = f2bf(ww[idx]);
}

// ---------------- kqT = BN(1x1 conv(x)) ; bf16 [B, N, CK] (channel-contiguous) ----------------
// grid: (NPIX/256, CK/8, NB)
__global__ __launch_bounds__(256) void kq_kernel(
    const float* __restrict__ x, const float* __restrict__ wk,
    const float* __restrict__ bk, const float* __restrict__ gamma,
    const float* __restrict__ beta, const float* __restrict__ rmean,
    const float* __restrict__ rvar, short* __restrict__ kqT)
{
    int n  = blockIdx.x * 256 + threadIdx.x;
    int c0 = blockIdx.y * 8;
    int b  = blockIdx.z;
    const float* xp = x + (size_t)b * CIN * NPIX + n;
    float acc[8] = {0,0,0,0,0,0,0,0};
    for (int c = 0; c < CIN; ++c) {
        float xv = xp[(size_t)c * NPIX];
        #pragma unroll
        for (int k = 0; k < 8; ++k)
            acc[k] = fmaf(wk[(c0 + k) * CIN + c], xv, acc[k]);
    }
    sx8 o;
    #pragma unroll
    for (int k = 0; k < 8; ++k) {
        int ck = c0 + k;
        float inv = gamma[ck] * rsqrtf(rvar[ck] + BN_EPS);
        o[k] = f2bf((acc[k] + bk[ck]) * inv + (beta[ck] - rmean[ck] * inv));
    }
    *(sx8*)&kqT[((size_t)b * NPIX + n) * CK + c0] = o;
}

// ---------------- value = 3x3 conv via MFMA implicit GEMM ; bf16 [B, CVC, N] ----------------
#define CSTRIDE 36
__global__ __launch_bounds__(256) void conv3_kernel(
    const short* __restrict__ xpad, const short* __restrict__ wvt,
    const float* __restrict__ bv, short* __restrict__ val)
{
    __shared__ __align__(16) short Xs[6 * 18 * CSTRIDE];

    const int tid  = threadIdx.x;
    const int wid  = tid >> 6;
    const int lane = tid & 63;
    const int l15  = lane & 15;
    const int quad = lane >> 4;

    const int rowT = blockIdx.x / 5, colT = blockIdx.x % 5;
    const int h0 = rowT * 4, w0 = colT * 16;
    const int cv0 = blockIdx.y * 64 + wid * 16;
    const int b   = blockIdx.z;

    const short* xb = xpad + (size_t)b * HP * WP * CIN;

    f32x4 acc[4];
    #pragma unroll
    for (int r = 0; r < 4; ++r) acc[r] = (f32x4){0.f, 0.f, 0.f, 0.f};

    for (int cc = 0; cc < CIN / 32; ++cc) {
        __syncthreads();
        #pragma unroll
        for (int i = 0; i < 2; ++i) {
            int e = tid + i * 256;
            if (e < 432) {
                int rc = e >> 2, l4 = e & 3;
                int row = rc / 18, col = rc % 18;
                sx8 v = *(const sx8*)&xb[(((size_t)(h0 + row)) * WP + (w0 + col)) * CIN + cc * 32 + l4 * 8];
                *(sx8*)&Xs[rc * CSTRIDE + l4 * 8] = v;
            }
        }
        __syncthreads();

        #pragma unroll
        for (int dw = 0; dw < 3; ++dw) {
            sx8 Bf[6];
            #pragma unroll
            for (int rr = 0; rr < 6; ++rr)
                Bf[rr] = *(const sx8*)&Xs[(rr * 18 + l15 + dw) * CSTRIDE + quad * 8];
            #pragma unroll
            for (int dh = 0; dh < 3; ++dh) {
                int tap = dh * 3 + dw;
                sx8 Af = *(const sx8*)&wvt[((size_t)(tap * 256 + cv0 + l15)) * CIN + cc * 32 + quad * 8];
                #pragma unroll
                for (int r = 0; r < 4; ++r)
                    acc[r] = __builtin_amdgcn_mfma_f32_16x16x32_bf16(Af, Bf[r + dh], acc[r], 0, 0, 0);
            }
        }
    }

    f32x4 bvv = *(const f32x4*)&bv[cv0 + quad * 4];
    #pragma unroll
    for (int r = 0; r < 4; ++r) {
        int n = (h0 + r) * IMW + w0 + l15;
        #pragma unroll
        for (int reg = 0; reg < 4; ++reg) {
            int cv = cv0 + quad * 4 + reg;
            val[((size_t)b * CVC + cv) * NPIX + n] = f2bf(acc[r][reg] + bvv[reg]);
        }
    }
}

// ---------------- MFMA flash attention ----------------
// kqT [B,N,CK] bf16; val [B,CVC,N] bf16; ctxT [B,N,CVC] bf16 out.
// S computed transposed (D[m][q]) so softmax is in-wave and P is m-contiguous in regs.
#define TQ 64
#define TK 64
#define KS_LD 136   // 272 B rows; frag reads (l15+quad)%8 -> uniform 8 groups (minimal)
#define VS_LD 72
#define PS_LD 72

__global__ __launch_bounds__(256) void attn_kernel(
    const short* __restrict__ kqT, const short* __restrict__ val,
    short* __restrict__ ctxT)
{
    __shared__ __align__(16) short Ks[TK][KS_LD];     // K chunk (Q staged here first)
    __shared__ __align__(16) short Vs[CVC][VS_LD];
    __shared__ __align__(16) short Pb[TQ][PS_LD];
    __shared__ float arow[TQ];
    __shared__ float lrow[TQ];

    const int tid  = threadIdx.x;
    const int wid  = tid >> 6;
    const int lane = tid & 63;
    const int l15  = lane & 15;
    const int quad = lane >> 4;

    // batch = blk&1 -> batches interleave across XCDs (each XCD L2 caches one batch's K/V)
    const int blk = blockIdx.x;
    const int b   = blk & 1;
    const int n0  = (blk >> 1) * TQ;

    const short* kqb = kqT + (size_t)b * NPIX * CK;
    const short* vb  = val + (size_t)b * CVC * NPIX;

    // K/Q staging slot map: s = tid + p*256 -> row = s>>4, c8 = (s&15)*8 (coalesced 256B rows)
    // stage Q tile into Ks
    #pragma unroll
    for (int p = 0; p < 4; ++p) {
        int s = tid + p * 256;
        int row = s >> 4, c8 = (s & 15) * 8;
        *(sx8*)&Ks[row][c8] = *(const sx8*)&kqb[(size_t)(n0 + row) * CK + c8];
    }
    __syncthreads();

    // Q fragments (B-operand for S^T): B[k=c (quad*8+j)][n=q (l15)], wave owns q-strip wid*16..+16
    sx8 qf[4];
    #pragma unroll
    for (int s = 0; s < 4; ++s)
        qf[s] = *(const sx8*)&Ks[wid * 16 + l15][s * 32 + quad * 8];

    // prefetch chunk 0 K/V into regs
    sx8 kreg[4], vreg[8];
    #pragma unroll
    for (int p = 0; p < 4; ++p) {
        int s = tid + p * 256;
        int row = s >> 4, c8 = (s & 15) * 8;
        kreg[p] = *(const sx8*)&kqb[(size_t)row * CK + c8];
    }
    #pragma unroll
    for (int p = 0; p < 8; ++p) {
        int cv = (tid >> 3) + p * 32, m8 = (tid & 7) * 8;
        vreg[p] = *(const sx8*)&vb[(size_t)cv * NPIX + m8];
    }

    float mq = -1e30f, lq = 0.f;   // online-softmax state for q = wid*16 + l15 (replicated over quads)
    f32x4 acc[4][4];               // PV acc: row q = qt*16+quad*4+r, col cv = wid*64+ct*16+l15
    #pragma unroll
    for (int qt = 0; qt < 4; ++qt)
        #pragma unroll
        for (int ct = 0; ct < 4; ++ct)
            acc[qt][ct] = (f32x4){0.f, 0.f, 0.f, 0.f};

    for (int m0 = 0; m0 < NPIX; m0 += TK) {
        __syncthreads();   // all waves done reading Ks/Vs/Pb from prev iter (or Q frags)
        // commit prefetched K/V to LDS
        #pragma unroll
        for (int p = 0; p < 4; ++p) {
            int s = tid + p * 256;
            int row = s >> 4, c8 = (s & 15) * 8;
            *(sx8*)&Ks[row][c8] = kreg[p];
        }
        #pragma unroll
        for (int p = 0; p < 8; ++p) {
            int cv = (tid >> 3) + p * 32, m8 = (tid & 7) * 8;
            *(sx8*)&Vs[cv][m8] = vreg[p];
        }
        __syncthreads();
        // prefetch next chunk
        if (m0 + TK < NPIX) {
            int m1 = m0 + TK;
            #pragma unroll
            for (int p = 0; p < 4; ++p) {
                int s = tid + p * 256;
                int row = s >> 4, c8 = (s & 15) * 8;
                kreg[p] = *(const sx8*)&kqb[(size_t)(m1 + row) * CK + c8];
            }
            #pragma unroll
            for (int p = 0; p < 8; ++p) {
                int cv = (tid >> 3) + p * 32, m8 = (tid & 7) * 8;
                vreg[p] = *(const sx8*)&vb[(size_t)cv * NPIX + m1 + m8];
            }
        }

        // ---- S^T: st[t2] = D[m = t2*16+quad*4+r][q = l15] for q-strip wid
        f32x4 st[4];
        #pragma unroll
        for (int t2 = 0; t2 < 4; ++t2) st[t2] = (f32x4){0.f, 0.f, 0.f, 0.f};
        #pragma unroll
        for (int s = 0; s < 4; ++s) {
            #pragma unroll
            for (int t2 = 0; t2 < 4; ++t2) {
                sx8 af = *(const sx8*)&Ks[t2 * 16 + l15][s * 32 + quad * 8];  // A[m=l15][k]
                st[t2] = __builtin_amdgcn_mfma_f32_16x16x32_bf16(af, qf[s], st[t2], 0, 0, 0);
            }
        }

        // ---- in-wave online softmax over m (16 in-reg values + xor16/xor32)
        float mx = st[0][0];
        #pragma unroll
        for (int t2 = 0; t2 < 4; ++t2)
            #pragma unroll
            for (int r = 0; r < 4; ++r)
                mx = fmaxf(mx, st[t2][r]);
        mx = fmaxf(mx, __shfl_xor(mx, 16));
        mx = fmaxf(mx, __shfl_xor(mx, 32));
        float mnew = fmaxf(mq, mx);
        float alpha = __expf(mq - mnew);
        mq = mnew;
        float sum = 0.f;
        #pragma unroll
        for (int t2 = 0; t2 < 4; ++t2) {
            #pragma unroll
            for (int r = 0; r < 4; ++r) {
                float p = __expf(st[t2][r] - mnew);
                st[t2][r] = p;
                sum += p;
            }
        }
        sum += __shfl_xor(sum, 16);
        sum += __shfl_xor(sum, 32);
        lq = lq * alpha + sum;

        if (quad == 0) arow[wid * 16 + l15] = alpha;
        // P -> LDS: rows q (wave-private strip), m-contiguous packed b64
        #pragma unroll
        for (int t2 = 0; t2 < 4; ++t2) {
            sx4 pw;
            #pragma unroll
            for (int r = 0; r < 4; ++r) pw[r] = f2bf(st[t2][r]);
            *(sx4*)&Pb[wid * 16 + l15][t2 * 16 + quad * 4] = pw;
        }
        __syncthreads();   // Pb + arow ready

        // ---- PV: wave covers cv quarter [wid*64, +64), all 64 q
        #pragma unroll
        for (int qt = 0; qt < 4; ++qt) {
            f32x4 a4 = *(const f32x4*)&arow[qt * 16 + quad * 4];
            #pragma unroll
            for (int ct = 0; ct < 4; ++ct)
                acc[qt][ct] *= a4;
        }
        #pragma unroll
        for (int s = 0; s < 2; ++s) {
            sx8 pa[4];
            #pragma unroll
            for (int qt = 0; qt < 4; ++qt)
                pa[qt] = *(const sx8*)&Pb[qt * 16 + l15][s * 32 + quad * 8];
            #pragma unroll
            for (int ct = 0; ct < 4; ++ct) {
                sx8 vf = *(const sx8*)&Vs[wid * 64 + ct * 16 + l15][s * 32 + quad * 8];
                #pragma unroll
                for (int qt = 0; qt < 4; ++qt)
                    acc[qt][ct] = __builtin_amdgcn_mfma_f32_16x16x32_bf16(pa[qt], vf, acc[qt][ct], 0, 0, 0);
            }
        }
    }

    if (quad == 0) lrow[wid * 16 + l15] = lq;
    __syncthreads();

    // epilogue: ctxT[b][n][cv] bf16
    #pragma unroll
    for (int qt = 0; qt < 4; ++qt) {
        f32x4 lv = *(const f32x4*)&lrow[qt * 16 + quad * 4];
        f32x4 inv;
        #pragma unroll
        for (int r = 0; r < 4; ++r) inv[r] = 1.0f / lv[r];
        #pragma unroll
        for (int ct = 0; ct < 4; ++ct) {
            int cv = wid * 64 + ct * 16 + l15;
            #pragma unroll
            for (int r = 0; r < 4; ++r) {
                int n = n0 + qt * 16 + quad * 4 + r;
                ctxT[((size_t)b * NPIX + n) * CVC + cv] = f2bf(acc[qt][ct][r] * inv[r]);
            }
        }
    }
}

// ---------------- out = 1x1 conv(ctx) + x via MFMA ; grid (100, 4, NB) ----------------
#define BS_LD 40
__global__ __launch_bounds__(256) void out_kernel(
    const short* __restrict__ ctxT, const short* __restrict__ wwb,
    const float* __restrict__ bw, const float* __restrict__ x,
    float* __restrict__ out)
{
    __shared__ __align__(16) short Bs[64][BS_LD];   // 64 n x 32 cv chunk

    const int tid  = threadIdx.x;
    const int wid  = tid >> 6;
    const int lane = tid & 63;
    const int l15  = lane & 15;
    const int quad = lane >> 4;

    const int n0  = blockIdx.x * 64;
    const int co0 = blockIdx.y * 64 + wid * 16;
    const int b   = blockIdx.z;
    const short* cb = ctxT + (size_t)b * NPIX * CVC;

    f32x4 acc[4];
    #pragma unroll
    for (int nt = 0; nt < 4; ++nt) acc[nt] = (f32x4){0.f, 0.f, 0.f, 0.f};

    for (int cc = 0; cc < CVC / 32; ++cc) {
        __syncthreads();
        *(sx8*)&Bs[tid >> 2][(tid & 3) * 8] =
            *(const sx8*)&cb[(size_t)(n0 + (tid >> 2)) * CVC + cc * 32 + (tid & 3) * 8];
        __syncthreads();
        sx8 af = *(const sx8*)&wwb[(size_t)(co0 + l15) * CVC + cc * 32 + quad * 8];  // A[co][cv]
        #pragma unroll
        for (int nt = 0; nt < 4; ++nt) {
            sx8 bf = *(const sx8*)&Bs[nt * 16 + l15][quad * 8];   // B[k=cv][n=pix]
            acc[nt] = __builtin_amdgcn_mfma_f32_16x16x32_bf16(af, bf, acc[nt], 0, 0, 0);
        }
    }

    f32x4 bv4 = *(const f32x4*)&bw[co0 + quad * 4];
    #pragma unroll
    for (int nt = 0; nt < 4; ++nt) {
        #pragma unroll
        for (int r = 0; r < 4; ++r) {
            int co = co0 + quad * 4 + r;
            int n  = n0 + nt * 16 + l15;
            size_t gi = ((size_t)b * COUTC + co) * NPIX + n;
            out[gi] = acc[nt][r] + bv4[r] + x[gi];
        }
    }
}

extern "C" void kernel_launch(void* const* d_in, const int* in_sizes, int n_in,
                              void* d_out, int out_size, void* d_ws, size_t ws_size,
                              hipStream_t stream)
{
    const float* x     = (const float*)d_in[0];
    const float* wk    = (const float*)d_in[1];
    const float* bk    = (const float*)d_in[2];
    const float* gamma = (const float*)d_in[3];
    const float* beta  = (const float*)d_in[4];
    const float* rmean = (const float*)d_in[5];
    const float* rvar  = (const float*)d_in[6];
    const float* wv    = (const float*)d_in[7];
    const float* bv    = (const float*)d_in[8];
    const float* ww    = (const float*)d_in[9];
    const float* bw    = (const float*)d_in[10];
    float* out = (float*)d_out;

    // ws (shorts): xpad | wvt | wwb | kqT | val | ctxT   (~24.6 MB)
    short* xpad  = (short*)d_ws;
    short* wvt   = xpad  + (size_t)NB * HP * WP * CIN;
    short* wwb   = wvt   + (size_t)9 * CVC * CIN;
    short* kqT   = wwb   + (size_t)COUTC * CVC;
    short* vbuf  = kqT   + (size_t)NB * NPIX * CK;
    short* ctxT  = vbuf  + (size_t)NB * CVC * NPIX;

    hipMemsetAsync(xpad, 0, (size_t)NB * HP * WP * CIN * sizeof(short), stream);

    pad_kernel  <<<dim3(NPIX/64, NB),           256, 0, stream>>>(x, xpad);
    wvt_kernel  <<<(9*CVC*CIN)/256,             256, 0, stream>>>(wv, wvt);
    wwb_kernel  <<<(COUTC*CVC)/256,             256, 0, stream>>>(ww, wwb);
    kq_kernel   <<<dim3(NPIX/256, CK/8,    NB), 256, 0, stream>>>(x, wk, bk, gamma, beta, rmean, rvar, kqT);
    conv3_kernel<<<dim3(100, CVC/64,       NB), 256, 0, stream>>>(xpad, wvt, bv, vbuf);
    attn_kernel <<<NB * (NPIX / TQ),            256, 0, stream>>>(kqT, vbuf, ctxT);
    out_kernel  <<<dim3(100, COUTC/64,     NB), 256, 0, stream>>>(ctxT, wwb, bw, x, out);
}

// Round 5
// 339.388 us; speedup vs baseline: 14.2895x; 1.2323x over previous
//
#include <hip/hip_runtime.h>
#include <math.h>

// Problem constants (fixed by setup_inputs)
#define NB   2
#define CIN  256
#define IMH  80
#define IMW  80
#define NPIX (IMH*IMW)   // 6400
#define CK   128
#define CVC  256
#define COUTC 256
#define BN_EPS 1e-5f
#define HP   82          // padded H/W (NHWC bf16 xpad)
#define WP   82
#define SPLIT 2
#define NC   (NPIX / SPLIT / 64)   // 50 K-chunks per split

typedef short sx8 __attribute__((ext_vector_type(8)));    // 8 bf16 in 4 VGPRs
typedef short sx4 __attribute__((ext_vector_type(4)));    // 4 bf16 in 2 VGPRs
typedef float f32x4 __attribute__((ext_vector_type(4)));

__device__ __forceinline__ short f2bf(float f) {
    unsigned u = __builtin_bit_cast(unsigned, f);
    u += 0x7fffu + ((u >> 16) & 1u);   // RNE
    return (short)(u >> 16);
}
__device__ __forceinline__ float bf2f(short s) {
    unsigned u = ((unsigned)(unsigned short)s) << 16;
    return __builtin_bit_cast(float, u);
}

// ---------------- xpad: NCHW fp32 -> NHWC-padded bf16 [B][82][82][256] ----------------
__global__ __launch_bounds__(256) void pad_kernel(const float* __restrict__ x,
                                                  short* __restrict__ xpad)
{
    __shared__ short T[64][258];
    const int tid = threadIdx.x;
    const int n0  = blockIdx.x * 64;
    const int b   = blockIdx.y;
    const float* xb = x + (size_t)b * CIN * NPIX;

    #pragma unroll 4
    for (int i = 0; i < 64; ++i) {
        int e = tid + i * 256;
        int pix = e & 63, c = e >> 6;
        T[pix][c] = f2bf(xb[(size_t)c * NPIX + n0 + pix]);
    }
    __syncthreads();
    #pragma unroll
    for (int i = 0; i < 8; ++i) {
        int e   = tid + i * 256;
        int pix = e >> 5;
        int cp  = (e & 31) * 8;
        int np  = n0 + pix;
        int hp  = np / IMW + 1, wp = np % IMW + 1;
        sx8 v = *(const sx8*)&T[pix][cp];
        *(sx8*)&xpad[(((size_t)b * HP + hp) * WP + wp) * CIN + cp] = v;
    }
}

// ---------------- wv [256][256][3][3] fp32 -> wv_t [9][256][256] bf16 ----------------
__global__ __launch_bounds__(256) void wvt_kernel(const float* __restrict__ wv,
                                                  short* __restrict__ wvt)
{
    int idx = blockIdx.x * 256 + threadIdx.x;
    int tap = idx >> 16;
    int cv  = (idx >> 8) & 255;
    int c   = idx & 255;
    wvt[idx] = f2bf(wv[((size_t)cv * CIN + c) * 9 + tap]);
}

// ---------------- ww [256][256] fp32 -> bf16 ----------------
__global__ __launch_bounds__(256) void wwb_kernel(const float* __restrict__ ww,
                                                  short* __restrict__ wwb)
{
    int idx = blockIdx.x * 256 + threadIdx.x;
    wwb[idx] = f2bf(ww[idx]);
}

// ---------------- wk + BN fold -> wkb bf16 [CK][CIN], bias2 fp32 [CK] ----------------
__global__ __launch_bounds__(256) void wkb_kernel(
    const float* __restrict__ wk, const float* __restrict__ bk,
    const float* __restrict__ gamma, const float* __restrict__ beta,
    const float* __restrict__ rmean, const float* __restrict__ rvar,
    short* __restrict__ wkb, float* __restrict__ bias2)
{
    int idx = blockIdx.x * 256 + threadIdx.x;   // CK*CIN
    int ck = idx >> 8;
    float inv = gamma[ck] * rsqrtf(rvar[ck] + BN_EPS);
    wkb[idx] = f2bf(wk[idx] * inv);
    if (idx < CK) {
        float invi = gamma[idx] * rsqrtf(rvar[idx] + BN_EPS);
        bias2[idx] = (bk[idx] - rmean[idx]) * invi + beta[idx];
    }
}

// ---------------- kqT = BN(1x1 conv) via MFMA ; bf16 [B, N, CK] ----------------
// grid (100, NB); block 256. Wave strip = 32 ck; B-frags direct from xpad (L2-hot).
__global__ __launch_bounds__(256) void kq_kernel(
    const short* __restrict__ xpad, const short* __restrict__ wkb,
    const float* __restrict__ bias2, short* __restrict__ kqT)
{
    __shared__ short T[64][136];
    const int tid  = threadIdx.x;
    const int wid  = tid >> 6;
    const int lane = tid & 63;
    const int l15  = lane & 15;
    const int quad = lane >> 4;
    const int n0 = blockIdx.x * 64;
    const int b  = blockIdx.y;
    const short* xb = xpad + (size_t)b * HP * WP * CIN;
    const int ck0 = wid * 32;

    const short* brow[4];
    #pragma unroll
    for (int nt = 0; nt < 4; ++nt) {
        int n = n0 + nt * 16 + l15;
        int hp = n / IMW + 1, wp = n % IMW + 1;
        brow[nt] = xb + ((size_t)hp * WP + wp) * CIN;
    }

    f32x4 acc[2][4];
    #pragma unroll
    for (int at = 0; at < 2; ++at)
        #pragma unroll
        for (int nt = 0; nt < 4; ++nt)
            acc[at][nt] = (f32x4){0.f, 0.f, 0.f, 0.f};

    for (int kc = 0; kc < CIN / 32; ++kc) {
        sx8 af0 = *(const sx8*)&wkb[(size_t)(ck0 + l15) * CIN + kc * 32 + quad * 8];
        sx8 af1 = *(const sx8*)&wkb[(size_t)(ck0 + 16 + l15) * CIN + kc * 32 + quad * 8];
        #pragma unroll
        for (int nt = 0; nt < 4; ++nt) {
            sx8 bf = *(const sx8*)&brow[nt][kc * 32 + quad * 8];
            acc[0][nt] = __builtin_amdgcn_mfma_f32_16x16x32_bf16(af0, bf, acc[0][nt], 0, 0, 0);
            acc[1][nt] = __builtin_amdgcn_mfma_f32_16x16x32_bf16(af1, bf, acc[1][nt], 0, 0, 0);
        }
    }

    #pragma unroll
    for (int at = 0; at < 2; ++at) {
        f32x4 b4 = *(const f32x4*)&bias2[ck0 + at * 16 + quad * 4];
        #pragma unroll
        for (int nt = 0; nt < 4; ++nt)
            #pragma unroll
            for (int r = 0; r < 4; ++r)
                T[nt * 16 + l15][ck0 + at * 16 + quad * 4 + r] = f2bf(acc[at][nt][r] + b4[r]);
    }
    __syncthreads();
    #pragma unroll
    for (int it = 0; it < 4; ++it) {
        int e = tid + it * 256;
        int row = e >> 4, c8 = (e & 15) * 8;
        *(sx8*)&kqT[((size_t)b * NPIX + n0 + row) * CK + c8] = *(const sx8*)&T[row][c8];
    }
}

// ---------------- value = 3x3 conv via MFMA implicit GEMM ; bf16 [B, CVC, N] ----------------
#define CSTRIDE 36
__global__ __launch_bounds__(256) void conv3_kernel(
    const short* __restrict__ xpad, const short* __restrict__ wvt,
    const float* __restrict__ bv, short* __restrict__ val)
{
    __shared__ __align__(16) short Xs[6 * 18 * CSTRIDE];

    const int tid  = threadIdx.x;
    const int wid  = tid >> 6;
    const int lane = tid & 63;
    const int l15  = lane & 15;
    const int quad = lane >> 4;

    const int rowT = blockIdx.x / 5, colT = blockIdx.x % 5;
    const int h0 = rowT * 4, w0 = colT * 16;
    const int cv0 = blockIdx.y * 64 + wid * 16;
    const int b   = blockIdx.z;

    const short* xb = xpad + (size_t)b * HP * WP * CIN;

    f32x4 acc[4];
    #pragma unroll
    for (int r = 0; r < 4; ++r) acc[r] = (f32x4){0.f, 0.f, 0.f, 0.f};

    for (int cc = 0; cc < CIN / 32; ++cc) {
        __syncthreads();
        #pragma unroll
        for (int i = 0; i < 2; ++i) {
            int e = tid + i * 256;
            if (e < 432) {
                int rc = e >> 2, l4 = e & 3;
                int row = rc / 18, col = rc % 18;
                sx8 v = *(const sx8*)&xb[(((size_t)(h0 + row)) * WP + (w0 + col)) * CIN + cc * 32 + l4 * 8];
                *(sx8*)&Xs[rc * CSTRIDE + l4 * 8] = v;
            }
        }
        __syncthreads();

        #pragma unroll
        for (int dw = 0; dw < 3; ++dw) {
            sx8 Bf[6];
            #pragma unroll
            for (int rr = 0; rr < 6; ++rr)
                Bf[rr] = *(const sx8*)&Xs[(rr * 18 + l15 + dw) * CSTRIDE + quad * 8];
            #pragma unroll
            for (int dh = 0; dh < 3; ++dh) {
                int tap = dh * 3 + dw;
                sx8 Af = *(const sx8*)&wvt[((size_t)(tap * 256 + cv0 + l15)) * CIN + cc * 32 + quad * 8];
                #pragma unroll
                for (int r = 0; r < 4; ++r)
                    acc[r] = __builtin_amdgcn_mfma_f32_16x16x32_bf16(Af, Bf[r + dh], acc[r], 0, 0, 0);
            }
        }
    }

    f32x4 bvv = *(const f32x4*)&bv[cv0 + quad * 4];
    #pragma unroll
    for (int r = 0; r < 4; ++r) {
        int n = (h0 + r) * IMW + w0 + l15;
        #pragma unroll
        for (int reg = 0; reg < 4; ++reg) {
            int cv = cv0 + quad * 4 + reg;
            val[((size_t)b * CVC + cv) * NPIX + n] = f2bf(acc[r][reg] + bvv[reg]);
        }
    }
}

// ---------------- MFMA flash attention, split-K, V direct-from-global ----------------
// Writes UNNORMALIZED partial O (bf16) + per-q (m,l).
#define TQ 64
#define TK 64
#define KS_LD 136
#define PS_LD 72

__global__ __launch_bounds__(256) void attn_kernel(
    const short* __restrict__ kqT, const short* __restrict__ val,
    short* __restrict__ opart, float* __restrict__ mpart, float* __restrict__ lpart)
{
    __shared__ __align__(16) short Ks[2][TK][KS_LD];   // 34816 B, double-buffered
    __shared__ __align__(16) short Pb[2][TQ][PS_LD];   //  9216 B x2
    __shared__ float arow[2][TQ];

    const int tid  = threadIdx.x;
    const int wid  = tid >> 6;
    const int lane = tid & 63;
    const int l15  = lane & 15;
    const int quad = lane >> 4;

    const int blk = blockIdx.x;             // b(2) x sp(2) x qtile(100)
    const int b   = blk & 1;                // XCD parity -> batch
    const int sp  = (blk >> 1) & 1;
    const int n0  = (blk >> 2) * TQ;
    const int mb  = sp * (NPIX / SPLIT);

    const short* kqb = kqT + (size_t)b * NPIX * CK;
    const short* vb  = val + (size_t)b * CVC * NPIX;

    // staging slot map (coalesced 256B rows of kqT)
    const int srow = tid >> 4;              // with +p*256: rows 0..63
    const int sc8  = (tid & 15) * 8;

    // Q fragments direct from global (B-operand: B[k=c][n=q], q = wid*16+l15)
    sx8 qf[4];
    #pragma unroll
    for (int s = 0; s < 4; ++s)
        qf[s] = *(const sx8*)&kqb[(size_t)(n0 + wid * 16 + l15) * CK + s * 32 + quad * 8];

    // K chunk 0 -> regs -> Ks[0]
    sx8 kreg[4];
    #pragma unroll
    for (int p = 0; p < 4; ++p)
        kreg[p] = *(const sx8*)&kqb[(size_t)(mb + srow + p * 16) * CK + sc8];
    #pragma unroll
    for (int p = 0; p < 4; ++p)
        *(sx8*)&Ks[0][srow + p * 16][sc8] = kreg[p];

    // V chunk 0 -> regs (each lane loads exactly its PV fragments; no LDS)
    sx8 vreg[8];
    #pragma unroll
    for (int s2 = 0; s2 < 2; ++s2)
        #pragma unroll
        for (int ct = 0; ct < 4; ++ct) {
            int cv = wid * 64 + ct * 16 + l15;
            vreg[s2 * 4 + ct] = *(const sx8*)&vb[(size_t)cv * NPIX + mb + s2 * 32 + quad * 8];
        }

    float mq = -1e30f, lq = 0.f;
    f32x4 acc[4][4];
    #pragma unroll
    for (int qt = 0; qt < 4; ++qt)
        #pragma unroll
        for (int ct = 0; ct < 4; ++ct)
            acc[qt][ct] = (f32x4){0.f, 0.f, 0.f, 0.f};

    __syncthreads();

    for (int i = 0; i < NC; ++i) {
        const int cur = i & 1;
        const int m0  = mb + i * TK;

        // prefetch next K chunk into regs (latency covered by S + softmax)
        if (i + 1 < NC) {
            #pragma unroll
            for (int p = 0; p < 4; ++p)
                kreg[p] = *(const sx8*)&kqb[(size_t)(m0 + TK + srow + p * 16) * CK + sc8];
        }

        // ---- S^T: D[m][q] for this wave's q-strip
        f32x4 st[4];
        #pragma unroll
        for (int t2 = 0; t2 < 4; ++t2) st[t2] = (f32x4){0.f, 0.f, 0.f, 0.f};
        #pragma unroll
        for (int s = 0; s < 4; ++s) {
            #pragma unroll
            for (int t2 = 0; t2 < 4; ++t2) {
                sx8 af = *(const sx8*)&Ks[cur][t2 * 16 + l15][s * 32 + quad * 8];
                st[t2] = __builtin_amdgcn_mfma_f32_16x16x32_bf16(af, qf[s], st[t2], 0, 0, 0);
            }
        }

        // ---- in-wave online softmax over m (quad-dim reduce: xor16, xor32)
        float mx = st[0][0];
        #pragma unroll
        for (int t2 = 0; t2 < 4; ++t2)
            #pragma unroll
            for (int r = 0; r < 4; ++r)
                mx = fmaxf(mx, st[t2][r]);
        mx = fmaxf(mx, __shfl_xor(mx, 16));
        mx = fmaxf(mx, __shfl_xor(mx, 32));
        float mnew = fmaxf(mq, mx);
        float alpha = __expf(mq - mnew);
        mq = mnew;
        float sum = 0.f;
        #pragma unroll
        for (int t2 = 0; t2 < 4; ++t2) {
            #pragma unroll
            for (int r = 0; r < 4; ++r) {
                float p = __expf(st[t2][r] - mnew);
                st[t2][r] = p;
                sum += p;
            }
        }
        sum += __shfl_xor(sum, 16);
        sum += __shfl_xor(sum, 32);
        lq = lq * alpha + sum;

        if (quad == 0) arow[cur][wid * 16 + l15] = alpha;
        #pragma unroll
        for (int t2 = 0; t2 < 4; ++t2) {
            sx4 pw;
            #pragma unroll
            for (int r = 0; r < 4; ++r) pw[r] = f2bf(st[t2][r]);
            *(sx4*)&Pb[cur][wid * 16 + l15][t2 * 16 + quad * 4] = pw;
        }

        // commit next K chunk (buffer cur^1: all reads of it finished before prev barrier)
        if (i + 1 < NC) {
            #pragma unroll
            for (int p = 0; p < 4; ++p)
                *(sx8*)&Ks[cur ^ 1][srow + p * 16][sc8] = kreg[p];
        }
        __syncthreads();   // the ONLY barrier per chunk: Pb/arow ready, K[cur^1] committed

        // ---- PV: wave covers cv quarter, all 64 q; V fragments straight from regs
        #pragma unroll
        for (int qt = 0; qt < 4; ++qt) {
            f32x4 a4 = *(const f32x4*)&arow[cur][qt * 16 + quad * 4];
            #pragma unroll
            for (int ct = 0; ct < 4; ++ct)
                acc[qt][ct] *= a4;
        }
        #pragma unroll
        for (int s2 = 0; s2 < 2; ++s2) {
            sx8 pa[4];
            #pragma unroll
            for (int qt = 0; qt < 4; ++qt)
                pa[qt] = *(const sx8*)&Pb[cur][qt * 16 + l15][s2 * 32 + quad * 8];
            #pragma unroll
            for (int ct = 0; ct < 4; ++ct) {
                #pragma unroll
                for (int qt = 0; qt < 4; ++qt)
                    acc[qt][ct] = __builtin_amdgcn_mfma_f32_16x16x32_bf16(pa[qt], vreg[s2 * 4 + ct], acc[qt][ct], 0, 0, 0);
            }
        }

        // reload V regs for next chunk (after last use; latency covered by next S phase)
        if (i + 1 < NC) {
            int m1 = m0 + TK;
            #pragma unroll
            for (int s2 = 0; s2 < 2; ++s2)
                #pragma unroll
                for (int ct = 0; ct < 4; ++ct) {
                    int cv = wid * 64 + ct * 16 + l15;
                    vreg[s2 * 4 + ct] = *(const sx8*)&vb[(size_t)cv * NPIX + m1 + s2 * 32 + quad * 8];
                }
        }
    }

    // ---- epilogue: unnormalized partial O (bf16) + m,l
    size_t obase = (size_t)(sp * NB + b) * NPIX + n0;
    #pragma unroll
    for (int qt = 0; qt < 4; ++qt)
        #pragma unroll
        for (int ct = 0; ct < 4; ++ct) {
            int cv = wid * 64 + ct * 16 + l15;
            #pragma unroll
            for (int r = 0; r < 4; ++r)
                opart[(obase + qt * 16 + quad * 4 + r) * CVC + cv] = f2bf(acc[qt][ct][r]);
        }
    if (quad == 0) {
        mpart[obase + wid * 16 + l15] = mq;
        lpart[obase + wid * 16 + l15] = lq;
    }
}

// ---------------- merge two split-K partials -> ctxT bf16 [B,N,CVC] ----------------
__global__ __launch_bounds__(256) void merge_kernel(
    const short* __restrict__ opart, const float* __restrict__ mpart,
    const float* __restrict__ lpart, short* __restrict__ ctxT)
{
    int idx = blockIdx.x * 256 + threadIdx.x;    // NB*NPIX*32 threads, 8 cv each
    int cv8 = (idx & 31) * 8;
    int n   = (idx >> 5) % NPIX;
    int b   = (idx >> 5) / NPIX;
    size_t r0 = (size_t)b * NPIX + n;
    size_t r1 = (size_t)(NB + b) * NPIX + n;
    float m0 = mpart[r0], m1 = mpart[r1];
    float l0 = lpart[r0], l1 = lpart[r1];
    float M  = fmaxf(m0, m1);
    float w0 = __expf(m0 - M), w1 = __expf(m1 - M);
    float rinv = 1.f / (w0 * l0 + w1 * l1);
    w0 *= rinv; w1 *= rinv;
    sx8 o0 = *(const sx8*)&opart[r0 * CVC + cv8];
    sx8 o1 = *(const sx8*)&opart[r1 * CVC + cv8];
    sx8 o;
    #pragma unroll
    for (int j = 0; j < 8; ++j)
        o[j] = f2bf(bf2f(o0[j]) * w0 + bf2f(o1[j]) * w1);
    *(sx8*)&ctxT[((size_t)b * NPIX + n) * CVC + cv8] = o;
}

// ---------------- out = 1x1 conv(ctx) + x via MFMA ; grid (100, 4, NB) ----------------
#define BS_LD 40
__global__ __launch_bounds__(256) void out_kernel(
    const short* __restrict__ ctxT, const short* __restrict__ wwb,
    const float* __restrict__ bw, const float* __restrict__ x,
    float* __restrict__ out)
{
    __shared__ __align__(16) short Bs[64][BS_LD];

    const int tid  = threadIdx.x;
    const int wid  = tid >> 6;
    const int lane = tid & 63;
    const int l15  = lane & 15;
    const int quad = lane >> 4;

    const int n0  = blockIdx.x * 64;
    const int co0 = blockIdx.y * 64 + wid * 16;
    const int b   = blockIdx.z;
    const short* cb = ctxT + (size_t)b * NPIX * CVC;

    f32x4 acc[4];
    #pragma unroll
    for (int nt = 0; nt < 4; ++nt) acc[nt] = (f32x4){0.f, 0.f, 0.f, 0.f};

    for (int cc = 0; cc < CVC / 32; ++cc) {
        __syncthreads();
        *(sx8*)&Bs[tid >> 2][(tid & 3) * 8] =
            *(const sx8*)&cb[(size_t)(n0 + (tid >> 2)) * CVC + cc * 32 + (tid & 3) * 8];
        __syncthreads();
        sx8 af = *(const sx8*)&wwb[(size_t)(co0 + l15) * CVC + cc * 32 + quad * 8];
        #pragma unroll
        for (int nt = 0; nt < 4; ++nt) {
            sx8 bf = *(const sx8*)&Bs[nt * 16 + l15][quad * 8];
            acc[nt] = __builtin_amdgcn_mfma_f32_16x16x32_bf16(af, bf, acc[nt], 0, 0, 0);
        }
    }

    f32x4 bv4 = *(const f32x4*)&bw[co0 + quad * 4];
    #pragma unroll
    for (int nt = 0; nt < 4; ++nt) {
        #pragma unroll
        for (int r = 0; r < 4; ++r) {
            int co = co0 + quad * 4 + r;
            int n  = n0 + nt * 16 + l15;
            size_t gi = ((size_t)b * COUTC + co) * NPIX + n;
            out[gi] = acc[nt][r] + bv4[r] + x[gi];
        }
    }
}

extern "C" void kernel_launch(void* const* d_in, const int* in_sizes, int n_in,
                              void* d_out, int out_size, void* d_ws, size_t ws_size,
                              hipStream_t stream)
{
    const float* x     = (const float*)d_in[0];
    const float* wk    = (const float*)d_in[1];
    const float* bk    = (const float*)d_in[2];
    const float* gamma = (const float*)d_in[3];
    const float* beta  = (const float*)d_in[4];
    const float* rmean = (const float*)d_in[5];
    const float* rvar  = (const float*)d_in[6];
    const float* wv    = (const float*)d_in[7];
    const float* bv    = (const float*)d_in[8];
    const float* ww    = (const float*)d_in[9];
    const float* bw    = (const float*)d_in[10];
    float* out = (float*)d_out;

    // ws (shorts): xpad | wvt | wwb | wkb | kqT | val | ctxT, then floats bias2|mpart|lpart (~25 MB)
    short* xpad  = (short*)d_ws;
    short* wvt   = xpad  + (size_t)NB * HP * WP * CIN;
    short* wwb   = wvt   + (size_t)9 * CVC * CIN;
    short* wkb   = wwb   + (size_t)COUTC * CVC;
    short* kqT   = wkb   + (size_t)CK * CIN;
    short* vbuf  = kqT   + (size_t)NB * NPIX * CK;
    short* ctxT  = vbuf  + (size_t)NB * CVC * NPIX;
    float* bias2 = (float*)(ctxT + (size_t)NB * NPIX * CVC);
    float* mpart = bias2 + CK;
    float* lpart = mpart + (size_t)SPLIT * NB * NPIX;

    // partial O (bf16, split x B x N x CVC) lives in d_out: exactly out_size*4 bytes,
    // fully consumed by merge_kernel before out_kernel overwrites d_out.
    short* opart = (short*)d_out;

    hipMemsetAsync(xpad, 0, (size_t)NB * HP * WP * CIN * sizeof(short), stream);

    pad_kernel  <<<dim3(NPIX/64, NB),           256, 0, stream>>>(x, xpad);
    wvt_kernel  <<<(9*CVC*CIN)/256,             256, 0, stream>>>(wv, wvt);
    wwb_kernel  <<<(COUTC*CVC)/256,             256, 0, stream>>>(ww, wwb);
    wkb_kernel  <<<(CK*CIN)/256,                256, 0, stream>>>(wk, bk, gamma, beta, rmean, rvar, wkb, bias2);
    kq_kernel   <<<dim3(NPIX/64, NB),           256, 0, stream>>>(xpad, wkb, bias2, kqT);
    conv3_kernel<<<dim3(100, CVC/64,       NB), 256, 0, stream>>>(xpad, wvt, bv, vbuf);
    attn_kernel <<<NB * SPLIT * (NPIX / TQ),    256, 0, stream>>>(kqT, vbuf, opart, mpart, lpart);
    merge_kernel<<<(NB*NPIX*32)/256,            256, 0, stream>>>(opart, mpart, lpart, ctxT);
    out_kernel  <<<dim3(100, COUTC/64,     NB), 256, 0, stream>>>(ctxT, wwb, bw, x, out);
}

// Round 6
// 273.618 us; speedup vs baseline: 17.7243x; 1.2404x over previous
//
#include <hip/hip_runtime.h>
#include <math.h>

// Problem constants (fixed by setup_inputs)
#define NB   2
#define CIN  256
#define IMH  80
#define IMW  80
#define NPIX (IMH*IMW)   // 6400
#define CK   128
#define CVC  256
#define COUTC 256
#define BN_EPS 1e-5f
#define HP   82          // padded H/W (NHWC bf16 xpad)
#define WP   82
#define SPLIT 2
#define NC   (NPIX / SPLIT / 64)   // 50 K-chunks per split
#define NMC  (NPIX / 64)           // 100 m-chunks per batch

typedef short sx8 __attribute__((ext_vector_type(8)));    // 8 bf16 in 4 VGPRs
typedef short sx4 __attribute__((ext_vector_type(4)));    // 4 bf16 in 2 VGPRs
typedef float f32x4 __attribute__((ext_vector_type(4)));

__device__ __forceinline__ short f2bf(float f) {
    unsigned u = __builtin_bit_cast(unsigned, f);
    u += 0x7fffu + ((u >> 16) & 1u);   // RNE
    return (short)(u >> 16);
}
__device__ __forceinline__ float bf2f(short s) {
    unsigned u = ((unsigned)(unsigned short)s) << 16;
    return __builtin_bit_cast(float, u);
}

// ---------------- xpad: NCHW fp32 -> NHWC-padded bf16 [B][82][82][256] ----------------
__global__ __launch_bounds__(256) void pad_kernel(const float* __restrict__ x,
                                                  short* __restrict__ xpad)
{
    __shared__ short T[64][258];
    const int tid = threadIdx.x;
    const int n0  = blockIdx.x * 64;
    const int b   = blockIdx.y;
    const float* xb = x + (size_t)b * CIN * NPIX;

    #pragma unroll 4
    for (int i = 0; i < 64; ++i) {
        int e = tid + i * 256;
        int pix = e & 63, c = e >> 6;
        T[pix][c] = f2bf(xb[(size_t)c * NPIX + n0 + pix]);
    }
    __syncthreads();
    #pragma unroll
    for (int i = 0; i < 8; ++i) {
        int e   = tid + i * 256;
        int pix = e >> 5;
        int cp  = (e & 31) * 8;
        int np  = n0 + pix;
        int hp  = np / IMW + 1, wp = np % IMW + 1;
        sx8 v = *(const sx8*)&T[pix][cp];
        *(sx8*)&xpad[(((size_t)b * HP + hp) * WP + wp) * CIN + cp] = v;
    }
}

// ---------------- wv [256][256][3][3] fp32 -> wv_t [9][256][256] bf16 ----------------
__global__ __launch_bounds__(256) void wvt_kernel(const float* __restrict__ wv,
                                                  short* __restrict__ wvt)
{
    int idx = blockIdx.x * 256 + threadIdx.x;
    int tap = idx >> 16;
    int cv  = (idx >> 8) & 255;
    int c   = idx & 255;
    wvt[idx] = f2bf(wv[((size_t)cv * CIN + c) * 9 + tap]);
}

// ---------------- ww [256][256] fp32 -> bf16 ----------------
__global__ __launch_bounds__(256) void wwb_kernel(const float* __restrict__ ww,
                                                  short* __restrict__ wwb)
{
    int idx = blockIdx.x * 256 + threadIdx.x;
    wwb[idx] = f2bf(ww[idx]);
}

// ---------------- wk + BN fold -> wkb bf16 [CK][CIN], bias2 fp32 [CK] ----------------
__global__ __launch_bounds__(256) void wkb_kernel(
    const float* __restrict__ wk, const float* __restrict__ bk,
    const float* __restrict__ gamma, const float* __restrict__ beta,
    const float* __restrict__ rmean, const float* __restrict__ rvar,
    short* __restrict__ wkb, float* __restrict__ bias2)
{
    int idx = blockIdx.x * 256 + threadIdx.x;   // CK*CIN
    int ck = idx >> 8;
    float inv = gamma[ck] * rsqrtf(rvar[ck] + BN_EPS);
    wkb[idx] = f2bf(wk[idx] * inv);
    if (idx < CK) {
        float invi = gamma[idx] * rsqrtf(rvar[idx] + BN_EPS);
        bias2[idx] = (bk[idx] - rmean[idx]) * invi + beta[idx];
    }
}

// ---------------- kqT = BN(1x1 conv) via MFMA ; bf16 [B, N, CK] ----------------
__global__ __launch_bounds__(256) void kq_kernel(
    const short* __restrict__ xpad, const short* __restrict__ wkb,
    const float* __restrict__ bias2, short* __restrict__ kqT)
{
    __shared__ short T[64][136];
    const int tid  = threadIdx.x;
    const int wid  = tid >> 6;
    const int lane = tid & 63;
    const int l15  = lane & 15;
    const int quad = lane >> 4;
    const int n0 = blockIdx.x * 64;
    const int b  = blockIdx.y;
    const short* xb = xpad + (size_t)b * HP * WP * CIN;
    const int ck0 = wid * 32;

    const short* brow[4];
    #pragma unroll
    for (int nt = 0; nt < 4; ++nt) {
        int n = n0 + nt * 16 + l15;
        int hp = n / IMW + 1, wp = n % IMW + 1;
        brow[nt] = xb + ((size_t)hp * WP + wp) * CIN;
    }

    f32x4 acc[2][4];
    #pragma unroll
    for (int at = 0; at < 2; ++at)
        #pragma unroll
        for (int nt = 0; nt < 4; ++nt)
            acc[at][nt] = (f32x4){0.f, 0.f, 0.f, 0.f};

    for (int kc = 0; kc < CIN / 32; ++kc) {
        sx8 af0 = *(const sx8*)&wkb[(size_t)(ck0 + l15) * CIN + kc * 32 + quad * 8];
        sx8 af1 = *(const sx8*)&wkb[(size_t)(ck0 + 16 + l15) * CIN + kc * 32 + quad * 8];
        #pragma unroll
        for (int nt = 0; nt < 4; ++nt) {
            sx8 bf = *(const sx8*)&brow[nt][kc * 32 + quad * 8];
            acc[0][nt] = __builtin_amdgcn_mfma_f32_16x16x32_bf16(af0, bf, acc[0][nt], 0, 0, 0);
            acc[1][nt] = __builtin_amdgcn_mfma_f32_16x16x32_bf16(af1, bf, acc[1][nt], 0, 0, 0);
        }
    }

    #pragma unroll
    for (int at = 0; at < 2; ++at) {
        f32x4 b4 = *(const f32x4*)&bias2[ck0 + at * 16 + quad * 4];
        #pragma unroll
        for (int nt = 0; nt < 4; ++nt)
            #pragma unroll
            for (int r = 0; r < 4; ++r)
                T[nt * 16 + l15][ck0 + at * 16 + quad * 4 + r] = f2bf(acc[at][nt][r] + b4[r]);
    }
    __syncthreads();
    #pragma unroll
    for (int it = 0; it < 4; ++it) {
        int e = tid + it * 256;
        int row = e >> 4, c8 = (e & 15) * 8;
        *(sx8*)&kqT[((size_t)b * NPIX + n0 + row) * CK + c8] = *(const sx8*)&T[row][c8];
    }
}

// ---------------- value = 3x3 conv via MFMA implicit GEMM ; bf16 [B, CVC, N] ----------------
#define CSTRIDE 36
__global__ __launch_bounds__(256) void conv3_kernel(
    const short* __restrict__ xpad, const short* __restrict__ wvt,
    const float* __restrict__ bv, short* __restrict__ val)
{
    __shared__ __align__(16) short Xs[6 * 18 * CSTRIDE];

    const int tid  = threadIdx.x;
    const int wid  = tid >> 6;
    const int lane = tid & 63;
    const int l15  = lane & 15;
    const int quad = lane >> 4;

    const int rowT = blockIdx.x / 5, colT = blockIdx.x % 5;
    const int h0 = rowT * 4, w0 = colT * 16;
    const int cv0 = blockIdx.y * 64 + wid * 16;
    const int b   = blockIdx.z;

    const short* xb = xpad + (size_t)b * HP * WP * CIN;

    f32x4 acc[4];
    #pragma unroll
    for (int r = 0; r < 4; ++r) acc[r] = (f32x4){0.f, 0.f, 0.f, 0.f};

    for (int cc = 0; cc < CIN / 32; ++cc) {
        __syncthreads();
        #pragma unroll
        for (int i = 0; i < 2; ++i) {
            int e = tid + i * 256;
            if (e < 432) {
                int rc = e >> 2, l4 = e & 3;
                int row = rc / 18, col = rc % 18;
                sx8 v = *(const sx8*)&xb[(((size_t)(h0 + row)) * WP + (w0 + col)) * CIN + cc * 32 + l4 * 8];
                *(sx8*)&Xs[rc * CSTRIDE + l4 * 8] = v;
            }
        }
        __syncthreads();

        #pragma unroll
        for (int dw = 0; dw < 3; ++dw) {
            sx8 Bf[6];
            #pragma unroll
            for (int rr = 0; rr < 6; ++rr)
                Bf[rr] = *(const sx8*)&Xs[(rr * 18 + l15 + dw) * CSTRIDE + quad * 8];
            #pragma unroll
            for (int dh = 0; dh < 3; ++dh) {
                int tap = dh * 3 + dw;
                sx8 Af = *(const sx8*)&wvt[((size_t)(tap * 256 + cv0 + l15)) * CIN + cc * 32 + quad * 8];
                #pragma unroll
                for (int r = 0; r < 4; ++r)
                    acc[r] = __builtin_amdgcn_mfma_f32_16x16x32_bf16(Af, Bf[r + dh], acc[r], 0, 0, 0);
            }
        }
    }

    f32x4 bvv = *(const f32x4*)&bv[cv0 + quad * 4];
    #pragma unroll
    for (int r = 0; r < 4; ++r) {
        int n = (h0 + r) * IMW + w0 + l15;
        #pragma unroll
        for (int reg = 0; reg < 4; ++reg) {
            int cv = cv0 + quad * 4 + reg;
            val[((size_t)b * CVC + cv) * NPIX + n] = f2bf(acc[r][reg] + bvv[reg]);
        }
    }
}

// ---------------- repack val [B,CVC,N] -> valF fragment-linear ----------------
// valF element ((((b*NMC+mc)*16+cvt)*2+s2)*4+qm)*128 + l15c*8 + mi
//   = V[m = mc*64 + s2*32 + qm*8 + mi][cv = cvt*16 + l15c]
// attn PV load then reads base + lane*16B: perfectly coalesced 1KB/instr.
__global__ __launch_bounds__(256) void repack_kernel(const short* __restrict__ val,
                                                     short* __restrict__ valF)
{
    const int tid = threadIdx.x;
    const int mc  = blockIdx.x;
    const int b   = blockIdx.y;
    const int mg  = tid & 7;          // m-group of 8
    const int cvb = tid >> 3;         // cv base (stride 32)
    const int s2  = mg >> 2, qm = mg & 3;
    #pragma unroll
    for (int p = 0; p < 8; ++p) {
        int cv = cvb + p * 32;
        sx8 v = *(const sx8*)&val[((size_t)b * CVC + cv) * NPIX + mc * 64 + mg * 8];
        size_t d = ((((size_t)(b * NMC + mc) * 16 + (cv >> 4)) * 2 + s2) * 4 + qm) * 128
                 + (cv & 15) * 8;
        *(sx8*)&valF[d] = v;
    }
}

// ---------------- MFMA flash attention, split-K, fragment-linear V ----------------
// Writes UNNORMALIZED partial O (bf16) + per-q (m,l).
#define TQ 64
#define TK 64
#define KS_LD 136
#define PS_LD 66    // 52224 B total LDS -> 3 blocks/CU

__global__ __launch_bounds__(256) void attn_kernel(
    const short* __restrict__ kqT, const short* __restrict__ valF,
    short* __restrict__ opart, float* __restrict__ mpart, float* __restrict__ lpart)
{
    __shared__ __align__(16) short Ks[2][TK][KS_LD];   // 34816 B, double-buffered
    __shared__ __align__(16) short Pb[2][TQ][PS_LD];   // 16896 B
    __shared__ float arow[2][TQ];                      //   512 B

    const int tid  = threadIdx.x;
    const int wid  = tid >> 6;
    const int lane = tid & 63;
    const int l15  = lane & 15;
    const int quad = lane >> 4;

    const int blk = blockIdx.x;             // b(2) x sp(2) x qtile(100)
    const int b   = blk & 1;                // XCD parity -> batch
    const int sp  = (blk >> 1) & 1;
    const int n0  = (blk >> 2) * TQ;
    const int mb  = sp * (NPIX / SPLIT);

    const short* kqb = kqT + (size_t)b * NPIX * CK;
    // fragment-linear V base for this wave: chunk stride 16384, ct stride 1024, s2 stride 512
    const short* vbase = valF + ((size_t)(b * NMC + sp * NC) * 16 + wid * 4) * 1024
                              + (size_t)lane * 8;

    const int srow = tid >> 4;
    const int sc8  = (tid & 15) * 8;

    // Q fragments direct from global (B-operand: B[k=c][n=q], q = wid*16+l15)
    sx8 qf[4];
    #pragma unroll
    for (int s = 0; s < 4; ++s)
        qf[s] = *(const sx8*)&kqb[(size_t)(n0 + wid * 16 + l15) * CK + s * 32 + quad * 8];

    // K chunk 0 -> regs -> Ks[0]
    sx8 kreg[4];
    #pragma unroll
    for (int p = 0; p < 4; ++p)
        kreg[p] = *(const sx8*)&kqb[(size_t)(mb + srow + p * 16) * CK + sc8];
    #pragma unroll
    for (int p = 0; p < 4; ++p)
        *(sx8*)&Ks[0][srow + p * 16][sc8] = kreg[p];

    // V chunk 0 -> regs (coalesced fragment-linear loads)
    sx8 vreg[8];
    #pragma unroll
    for (int s2 = 0; s2 < 2; ++s2)
        #pragma unroll
        for (int ct = 0; ct < 4; ++ct)
            vreg[s2 * 4 + ct] = *(const sx8*)&vbase[ct * 1024 + s2 * 512];

    float mq = -1e30f, lq = 0.f;
    f32x4 acc[4][4];
    #pragma unroll
    for (int qt = 0; qt < 4; ++qt)
        #pragma unroll
        for (int ct = 0; ct < 4; ++ct)
            acc[qt][ct] = (f32x4){0.f, 0.f, 0.f, 0.f};

    __syncthreads();

    for (int i = 0; i < NC; ++i) {
        const int cur = i & 1;
        const int m0  = mb + i * TK;

        // prefetch next K chunk into regs (latency covered by S + softmax)
        if (i + 1 < NC) {
            #pragma unroll
            for (int p = 0; p < 4; ++p)
                kreg[p] = *(const sx8*)&kqb[(size_t)(m0 + TK + srow + p * 16) * CK + sc8];
        }

        // ---- S^T: D[m][q] for this wave's q-strip
        f32x4 st[4];
        #pragma unroll
        for (int t2 = 0; t2 < 4; ++t2) st[t2] = (f32x4){0.f, 0.f, 0.f, 0.f};
        #pragma unroll
        for (int s = 0; s < 4; ++s) {
            #pragma unroll
            for (int t2 = 0; t2 < 4; ++t2) {
                sx8 af = *(const sx8*)&Ks[cur][t2 * 16 + l15][s * 32 + quad * 8];
                st[t2] = __builtin_amdgcn_mfma_f32_16x16x32_bf16(af, qf[s], st[t2], 0, 0, 0);
            }
        }

        // ---- in-wave online softmax over m (quad-dim reduce: xor16, xor32)
        float mx = st[0][0];
        #pragma unroll
        for (int t2 = 0; t2 < 4; ++t2)
            #pragma unroll
            for (int r = 0; r < 4; ++r)
                mx = fmaxf(mx, st[t2][r]);
        mx = fmaxf(mx, __shfl_xor(mx, 16));
        mx = fmaxf(mx, __shfl_xor(mx, 32));
        float mnew = fmaxf(mq, mx);
        float alpha = __expf(mq - mnew);
        mq = mnew;
        float sum = 0.f;
        #pragma unroll
        for (int t2 = 0; t2 < 4; ++t2) {
            #pragma unroll
            for (int r = 0; r < 4; ++r) {
                float p = __expf(st[t2][r] - mnew);
                st[t2][r] = p;
                sum += p;
            }
        }
        sum += __shfl_xor(sum, 16);
        sum += __shfl_xor(sum, 32);
        lq = lq * alpha + sum;

        if (quad == 0) arow[cur][wid * 16 + l15] = alpha;
        #pragma unroll
        for (int t2 = 0; t2 < 4; ++t2) {
            sx4 pw;
            #pragma unroll
            for (int r = 0; r < 4; ++r) pw[r] = f2bf(st[t2][r]);
            *(sx4*)&Pb[cur][wid * 16 + l15][t2 * 16 + quad * 4] = pw;
        }

        // commit next K chunk (buffer cur^1: reads of it finished before prev barrier)
        if (i + 1 < NC) {
            #pragma unroll
            for (int p = 0; p < 4; ++p)
                *(sx8*)&Ks[cur ^ 1][srow + p * 16][sc8] = kreg[p];
        }
        __syncthreads();   // the ONLY barrier per chunk

        // ---- PV: wave covers cv quarter, all 64 q; V fragments from regs
        #pragma unroll
        for (int qt = 0; qt < 4; ++qt) {
            f32x4 a4 = *(const f32x4*)&arow[cur][qt * 16 + quad * 4];
            #pragma unroll
            for (int ct = 0; ct < 4; ++ct)
                acc[qt][ct] *= a4;
        }
        #pragma unroll
        for (int s2 = 0; s2 < 2; ++s2) {
            sx8 pa[4];
            #pragma unroll
            for (int qt = 0; qt < 4; ++qt)
                pa[qt] = *(const sx8*)&Pb[cur][qt * 16 + l15][s2 * 32 + quad * 8];
            #pragma unroll
            for (int ct = 0; ct < 4; ++ct) {
                #pragma unroll
                for (int qt = 0; qt < 4; ++qt)
                    acc[qt][ct] = __builtin_amdgcn_mfma_f32_16x16x32_bf16(pa[qt], vreg[s2 * 4 + ct], acc[qt][ct], 0, 0, 0);
            }
        }

        // reload V regs for next chunk (after last use; hidden by next S phase)
        if (i + 1 < NC) {
            #pragma unroll
            for (int s2 = 0; s2 < 2; ++s2)
                #pragma unroll
                for (int ct = 0; ct < 4; ++ct)
                    vreg[s2 * 4 + ct] = *(const sx8*)&vbase[(size_t)(i + 1) * 16384 + ct * 1024 + s2 * 512];
        }
    }

    // ---- epilogue: unnormalized partial O (bf16) + m,l
    size_t obase = (size_t)(sp * NB + b) * NPIX + n0;
    #pragma unroll
    for (int qt = 0; qt < 4; ++qt)
        #pragma unroll
        for (int ct = 0; ct < 4; ++ct) {
            int cv = wid * 64 + ct * 16 + l15;
            #pragma unroll
            for (int r = 0; r < 4; ++r)
                opart[(obase + qt * 16 + quad * 4 + r) * CVC + cv] = f2bf(acc[qt][ct][r]);
        }
    if (quad == 0) {
        mpart[obase + wid * 16 + l15] = mq;
        lpart[obase + wid * 16 + l15] = lq;
    }
}

// ---------------- out = 1x1 conv(merge(opart)) + x via MFMA ; grid (100, 4, NB) ----------------
#define BS_LD 40
__global__ __launch_bounds__(256) void out_kernel(
    const short* __restrict__ opart, const float* __restrict__ mpart,
    const float* __restrict__ lpart, const short* __restrict__ wwb,
    const float* __restrict__ bw, const float* __restrict__ x,
    float* __restrict__ out)
{
    __shared__ __align__(16) short Bs[64][BS_LD];
    __shared__ float w0s[64], w1s[64];

    const int tid  = threadIdx.x;
    const int wid  = tid >> 6;
    const int lane = tid & 63;
    const int l15  = lane & 15;
    const int quad = lane >> 4;

    const int n0  = blockIdx.x * 64;
    const int co0 = blockIdx.y * 64 + wid * 16;
    const int b   = blockIdx.z;

    // per-n split-merge weights
    if (tid < 64) {
        int n = n0 + tid;
        size_t r0 = (size_t)b * NPIX + n;
        size_t r1 = (size_t)(NB + b) * NPIX + n;
        float m0 = mpart[r0], m1 = mpart[r1];
        float l0 = lpart[r0], l1 = lpart[r1];
        float M  = fmaxf(m0, m1);
        float w0 = __expf(m0 - M), w1 = __expf(m1 - M);
        float rinv = 1.f / (w0 * l0 + w1 * l1);
        w0s[tid] = w0 * rinv;
        w1s[tid] = w1 * rinv;
    }

    const int srow = tid >> 2;
    const int sc8  = (tid & 3) * 8;
    const short* o0p = opart + ((size_t)b * NPIX + n0 + srow) * CVC + sc8;
    const short* o1p = o0p + (size_t)NB * NPIX * CVC;

    f32x4 acc[4];
    #pragma unroll
    for (int nt = 0; nt < 4; ++nt) acc[nt] = (f32x4){0.f, 0.f, 0.f, 0.f};

    for (int cc = 0; cc < CVC / 32; ++cc) {
        __syncthreads();
        {
            sx8 a = *(const sx8*)&o0p[cc * 32];
            sx8 bq = *(const sx8*)&o1p[cc * 32];
            float w0 = w0s[srow], w1 = w1s[srow];
            sx8 o;
            #pragma unroll
            for (int j = 0; j < 8; ++j)
                o[j] = f2bf(bf2f(a[j]) * w0 + bf2f(bq[j]) * w1);
            *(sx8*)&Bs[srow][sc8] = o;
        }
        __syncthreads();
        sx8 af = *(const sx8*)&wwb[(size_t)(co0 + l15) * CVC + cc * 32 + quad * 8];
        #pragma unroll
        for (int nt = 0; nt < 4; ++nt) {
            sx8 bf = *(const sx8*)&Bs[nt * 16 + l15][quad * 8];
            acc[nt] = __builtin_amdgcn_mfma_f32_16x16x32_bf16(af, bf, acc[nt], 0, 0, 0);
        }
    }

    f32x4 bv4 = *(const f32x4*)&bw[co0 + quad * 4];
    #pragma unroll
    for (int nt = 0; nt < 4; ++nt) {
        #pragma unroll
        for (int r = 0; r < 4; ++r) {
            int co = co0 + quad * 4 + r;
            int n  = n0 + nt * 16 + l15;
            size_t gi = ((size_t)b * COUTC + co) * NPIX + n;
            out[gi] = acc[nt][r] + bv4[r] + x[gi];
        }
    }
}

extern "C" void kernel_launch(void* const* d_in, const int* in_sizes, int n_in,
                              void* d_out, int out_size, void* d_ws, size_t ws_size,
                              hipStream_t stream)
{
    const float* x     = (const float*)d_in[0];
    const float* wk    = (const float*)d_in[1];
    const float* bk    = (const float*)d_in[2];
    const float* gamma = (const float*)d_in[3];
    const float* beta  = (const float*)d_in[4];
    const float* rmean = (const float*)d_in[5];
    const float* rvar  = (const float*)d_in[6];
    const float* wv    = (const float*)d_in[7];
    const float* bv    = (const float*)d_in[8];
    const float* ww    = (const float*)d_in[9];
    const float* bw    = (const float*)d_in[10];
    float* out = (float*)d_out;

    // ws layout (shorts):
    //   overlay region R (14.62 MB): [xpad 3442688][wvt 589824][val 3276800]
    //     -> reused as opart (13.1 MB) once xpad/wvt/val are dead (attn runs after
    //        kq/conv3/repack; out consumes opart last)
    //   persistent: wwb | wkb | kqT | valF | bias2(f32) | mpart(f32) | lpart(f32)
    short* xpad  = (short*)d_ws;
    short* wvt   = xpad + (size_t)NB * HP * WP * CIN;                 // 3442688
    short* vbuf  = wvt + (size_t)9 * CVC * CIN;                       // +589824
    short* opart = xpad;                                              // overlay
    short* wwb   = vbuf + (size_t)NB * CVC * NPIX;                    // end of R
    short* wkb   = wwb  + (size_t)COUTC * CVC;
    short* kqT   = wkb  + (size_t)CK * CIN;
    short* valF  = kqT  + (size_t)NB * NPIX * CK;
    float* bias2 = (float*)(valF + (size_t)NB * NPIX * CVC);
    float* mpart = bias2 + CK;
    float* lpart = mpart + (size_t)SPLIT * NB * NPIX;

    hipMemsetAsync(xpad, 0, (size_t)NB * HP * WP * CIN * sizeof(short), stream);

    pad_kernel   <<<dim3(NPIX/64, NB),          256, 0, stream>>>(x, xpad);
    wvt_kernel   <<<(9*CVC*CIN)/256,            256, 0, stream>>>(wv, wvt);
    wwb_kernel   <<<(COUTC*CVC)/256,            256, 0, stream>>>(ww, wwb);
    wkb_kernel   <<<(CK*CIN)/256,               256, 0, stream>>>(wk, bk, gamma, beta, rmean, rvar, wkb, bias2);
    kq_kernel    <<<dim3(NPIX/64, NB),          256, 0, stream>>>(xpad, wkb, bias2, kqT);
    conv3_kernel <<<dim3(100, CVC/64,      NB), 256, 0, stream>>>(xpad, wvt, bv, vbuf);
    repack_kernel<<<dim3(NMC, NB),              256, 0, stream>>>(vbuf, valF);
    attn_kernel  <<<NB * SPLIT * (NPIX / TQ),   256, 0, stream>>>(kqT, valF, opart, mpart, lpart);
    out_kernel   <<<dim3(100, COUTC/64,    NB), 256, 0, stream>>>(opart, mpart, lpart, wwb, bw, x, out);
}